// Round 6
// baseline (1363.318 us; speedup 1.0000x reference)
//
#include <hip/hip_runtime.h>

// ---------------------------------------------------------------------------
// LightGCN-style propagation, 4 independent bipartite graphs.
// R9: software-pipelined gather SpMM. R8b profile: fused N-side spmm is the
// top dispatch (184us/layer) at 56% HBM ceiling, VALUBusy 43%, occupancy 80%
// -> latency-bound on the pairs->gather dependent chain (~6.4 waves/SIMD
// covering 200-900cy gather latency). Fix:
//   - pairs prefetched 2 iterations ahead, row-gathers 1 iteration ahead;
//     peeled drain steps keep the steady-state body conditional-free
//     (degree is wave-uniform so pipeline branches are uniform).
//   - acc as float2 ext-vectors -> v_pk_fma_f32 (halves FMA inst count).
//   - nontemporal pair loads (streamed once; keep L2 for gather rows).
// Build (R6-R8): countB -> scanB -> partition (packed (src|dl<<17,val)) ->
// permute (per-bucket LDS counting sort -> CSR off[] + pairs), all
// coalesced, no global atomics. Fused multi-graph dispatches via desc tables.
// ---------------------------------------------------------------------------

#define D 128
#define NC 64          // partition chunks per stream
#define TILE_CAP 7168  // permute LDS tile capacity (edges)
#define MAX_NB 512     // max dest-buckets per stream

// native clang vectors (accepted by __builtin_nontemporal_load / packed fma)
typedef int   vint2   __attribute__((ext_vector_type(2)));
typedef int   vint4   __attribute__((ext_vector_type(4)));
typedef float vfloat2 __attribute__((ext_vector_type(2)));
typedef float vfloat4 __attribute__((ext_vector_type(4)));

// ---- bf16 helpers (RNE pack, bit-shift unpack) ----
__device__ __forceinline__ unsigned f2bf(float f) {
    unsigned u = __float_as_uint(f);
    u += 0x7FFFu + ((u >> 16) & 1u);
    return u >> 16;
}
__device__ __forceinline__ float bflo(unsigned u) { return __uint_as_float(u << 16); }
__device__ __forceinline__ float bfhi(unsigned u) { return __uint_as_float(u & 0xFFFF0000u); }

// ---- fp32 -> bf16 row conversion, fused over graphs ----
struct CvtG { const float* x; uint4* y; int n8, blkBase; };
struct CvtG4 { CvtG c[4]; };

__global__ __launch_bounds__(256) void cvt_bf16_kernel(CvtG4 Cd)
{
    int blk = blockIdx.x;
    int gi = (blk >= Cd.c[1].blkBase) + (blk >= Cd.c[2].blkBase)
           + (blk >= Cd.c[3].blkBase);
    const CvtG E = Cd.c[gi];
    int i = (blk - E.blkBase) * 256 + threadIdx.x;
    if (i >= E.n8) return;
    const float4* xp = (const float4*)E.x + (size_t)i * 2;
    float4 a = xp[0], b = xp[1];
    uint4 o;
    o.x = f2bf(a.x) | (f2bf(a.y) << 16);
    o.y = f2bf(a.z) | (f2bf(a.w) << 16);
    o.z = f2bf(b.x) | (f2bf(b.y) << 16);
    o.w = f2bf(b.z) | (f2bf(b.w) << 16);
    E.y[i] = o;
}

// ---- per-(graph,dir) stream descriptor ----
struct BStream {
    const int* dst; const int* src; const float* vals;
    int2* staged;        // K3 output (src|dl<<17, val), bucket-major (d_out)
    int2* pairs;         // final CSR pairs
    int* off;            // final CSR offsets [n+1]
    int nnz, n, wshift, nb, cbase;
};
struct B8 {
    BStream s[8];
    int* cnt;            // [sum(nb+1)][NC]: counts -> cursor starts (K2 rewrite)
    int* gBB;            // [sum(nb+1)]: bucket bases + per-stream sentinel
    int pb[8];           // permute-block base per stream
};

// ---- K1: coarse bucket histogram, one dst pass (nt streaming reads) ----
__global__ __launch_bounds__(512) void countB_kernel(B8 G)
{
    const BStream S = G.s[blockIdx.y];
    int c = blockIdx.x;
    __shared__ int h[MAX_NB];
    for (int i = threadIdx.x; i < S.nb; i += 512) h[i] = 0;
    __syncthreads();
    int len = (((S.nnz + NC - 1) / NC) + 3) & ~3;
    int e0 = c * len, e1 = min(S.nnz, e0 + len);
    if (e0 < e1) {
        int nq = (e1 - e0) >> 2;
        const vint4* dq = (const vint4*)(S.dst + e0);
        for (int i = threadIdx.x; i < nq; i += 512) {
            vint4 v = __builtin_nontemporal_load(&dq[i]);
            atomicAdd(&h[v.x >> S.wshift], 1);
            atomicAdd(&h[v.y >> S.wshift], 1);
            atomicAdd(&h[v.z >> S.wshift], 1);
            atomicAdd(&h[v.w >> S.wshift], 1);
        }
        for (int e = e0 + (nq << 2) + (int)threadIdx.x; e < e1; e += 512)
            atomicAdd(&h[S.dst[e] >> S.wshift], 1);
    }
    __syncthreads();
    int* out = G.cnt + (size_t)S.cbase * NC;
    for (int i = threadIdx.x; i < S.nb; i += 512) out[(size_t)i * NC + c] = h[i];
}

// ---- K2: bucket totals + exscan -> bases and per-chunk cursor starts ----
__global__ __launch_bounds__(512) void scanB_kernel(B8 G)
{
    const BStream S = G.s[blockIdx.x];
    int* cnt = G.cnt + (size_t)S.cbase * NC;
    int* bb  = G.gBB + S.cbase;
    __shared__ int wsum[8];
    int b = threadIdx.x;
    int t = 0;
    if (b < S.nb) {
        int* row = cnt + (size_t)b * NC;
        int run = 0;
        #pragma unroll
        for (int c = 0; c < NC; ++c) { int v = row[c]; row[c] = run; run += v; }
        t = run;
    }
    int lane = b & 63, w = b >> 6;
    int x = t;
    #pragma unroll
    for (int s = 1; s < 64; s <<= 1) {
        int y = __shfl_up(x, s, 64);
        if (lane >= s) x += y;
    }
    if (lane == 63) wsum[w] = x;
    __syncthreads();
    if (b == 0) {
        int run = 0;
        #pragma unroll
        for (int i = 0; i < 8; ++i) { int v = wsum[i]; wsum[i] = run; run += v; }
    }
    __syncthreads();
    int excl = wsum[w] + x - t;
    if (b < S.nb) {
        bb[b] = excl;
        int* row = cnt + (size_t)b * NC;
        #pragma unroll
        for (int c = 0; c < NC; ++c) row[c] += excl;
    }
    if (b == 0) { bb[S.nb] = S.nnz; S.off[S.n] = S.nnz; }
}

// ---- K3: partition edges bucket-major, packed (src|dl<<17, val) ----
__global__ __launch_bounds__(512) void partition_kernel(B8 G)
{
    const BStream S = G.s[blockIdx.y];
    int c = blockIdx.x;
    __shared__ int cur[MAX_NB];
    const int* cs = G.cnt + (size_t)S.cbase * NC;
    for (int i = threadIdx.x; i < S.nb; i += 512) cur[i] = cs[(size_t)i * NC + c];
    __syncthreads();
    int len = (((S.nnz + NC - 1) / NC) + 3) & ~3;
    int e0 = c * len, e1 = min(S.nnz, e0 + len);
    if (e0 >= e1) return;
    int smask = (1 << S.wshift) - 1;
    int nq = (e1 - e0) >> 2;
    const vint4*   dq = (const vint4*)(S.dst + e0);
    const vint4*   sq = (const vint4*)(S.src + e0);
    const vfloat4* vq = (const vfloat4*)(S.vals + e0);
    for (int i = threadIdx.x; i < nq; i += 512) {
        vint4 dv = __builtin_nontemporal_load(&dq[i]);
        vint4 sv = __builtin_nontemporal_load(&sq[i]);
        vfloat4 vv = __builtin_nontemporal_load(&vq[i]);
        int p;
        p = atomicAdd(&cur[dv.x >> S.wshift], 1);
        S.staged[p] = make_int2(sv.x | ((dv.x & smask) << 17), __float_as_int(vv.x));
        p = atomicAdd(&cur[dv.y >> S.wshift], 1);
        S.staged[p] = make_int2(sv.y | ((dv.y & smask) << 17), __float_as_int(vv.y));
        p = atomicAdd(&cur[dv.z >> S.wshift], 1);
        S.staged[p] = make_int2(sv.z | ((dv.z & smask) << 17), __float_as_int(vv.z));
        p = atomicAdd(&cur[dv.w >> S.wshift], 1);
        S.staged[p] = make_int2(sv.w | ((dv.w & smask) << 17), __float_as_int(vv.w));
    }
    for (int e = e0 + (nq << 2) + (int)threadIdx.x; e < e1; e += 512) {
        int d = S.dst[e];
        int p = atomicAdd(&cur[d >> S.wshift], 1);
        S.staged[p] = make_int2(S.src[e] | ((d & smask) << 17), __float_as_int(S.vals[e]));
    }
}

// ---- K4: per-bucket dest-sort through LDS; writes CSR off[] + pairs ----
__global__ __launch_bounds__(512) void permute_kernel(B8 G)
{
    int gb = blockIdx.x;
    int s = 0;
    #pragma unroll
    for (int i = 1; i < 8; ++i) s += (gb >= G.pb[i]);
    const BStream S = G.s[s];
    int b = gb - G.pb[s];
    const int* bb = G.gBB + S.cbase;
    int B0 = bb[b], B1 = bb[b + 1];
    int cnt = B1 - B0;
    int span = 1 << S.wshift;
    int dbase = b << S.wshift;

    __shared__ int2 tile[TILE_CAP];
    __shared__ int cursor[MAX_NB];
    __shared__ int wsum[8];
    int tid = threadIdx.x;

    for (int i = tid; i < span; i += 512) cursor[i] = 0;
    __syncthreads();
    for (int i = B0 + tid; i < B1; i += 512)
        atomicAdd(&cursor[((unsigned)S.staged[i].x) >> 17], 1);
    __syncthreads();

    // exclusive scan over span (<=512) counts
    int v = (tid < span) ? cursor[tid] : 0;
    int lane = tid & 63, w = tid >> 6;
    int x = v;
    #pragma unroll
    for (int st = 1; st < 64; st <<= 1) {
        int y = __shfl_up(x, st, 64);
        if (lane >= st) x += y;
    }
    if (lane == 63) wsum[w] = x;
    __syncthreads();
    if (tid == 0) {
        int run = 0;
        #pragma unroll
        for (int i = 0; i < 8; ++i) { int t = wsum[i]; wsum[i] = run; run += t; }
    }
    __syncthreads();
    int excl = wsum[w] + x - v;
    __syncthreads();
    if (tid < span) {
        int d = dbase + tid;
        if (d < S.n) S.off[d] = B0 + excl;
        cursor[tid] = excl;
    }
    __syncthreads();

    if (cnt <= TILE_CAP) {
        for (int i = B0 + tid; i < B1; i += 512) {
            int2 pe = S.staged[i];
            int dl = ((unsigned)pe.x) >> 17;
            int p = atomicAdd(&cursor[dl], 1);
            tile[p] = make_int2(pe.x & 0x1FFFF, pe.y);
        }
        __syncthreads();
        for (int i = tid; i < cnt; i += 512) S.pairs[B0 + i] = tile[i];
    } else {
        // statistically-never fallback; staged != pairs so no in-place hazard
        for (int i = B0 + tid; i < B1; i += 512) {
            int2 pe = S.staged[i];
            int dl = ((unsigned)pe.x) >> 17;
            int p = atomicAdd(&cursor[dl], 1);
            S.pairs[B0 + p] = make_int2(pe.x & 0x1FFFF, pe.y);
        }
    }
}

// ---- gather SpMM, fused over graphs, software-pipelined ----
// MODE 0: y = acc                          (P-side -> t)
// MODE 1: y = acc; out = aux(emb) + acc    (N-side layer 1)
// MODE 2: y = acc; out += acc              (N-side layer 2)
// MODE 3: out = (out + acc) * 0.25         (N-side layer 3)
struct SpmmG {
    const unsigned short* x;   // bf16 [n_src][128]
    unsigned short* y;         // bf16 [n_dst][128]
    float* out;                // fp32 [n_dst][128]
    const float* aux;          // fp32 emb (MODE 1)
    const int* off; const int2* pairs;
    int n_dst, blkBase;
};
struct SpmmG4 { SpmmG g[4]; };

__device__ __forceinline__ int2 ldp_nt(const int2* p) {
    vint2 v = __builtin_nontemporal_load((const vint2*)p);
    return make_int2(v.x, v.y);
}
__device__ __forceinline__ uint4 grow(const unsigned short* x, int src, int l16) {
    return ((const uint4*)(x + ((long)src << 7)))[l16];
}
__device__ __forceinline__ void fma8(vfloat2 a[4], uint4 g, float v) {
    vfloat2 vv; vv.x = v; vv.y = v;
    vfloat2 u;
    u.x = bflo(g.x); u.y = bfhi(g.x); a[0] = u * vv + a[0];
    u.x = bflo(g.y); u.y = bfhi(g.y); a[1] = u * vv + a[1];
    u.x = bflo(g.z); u.y = bfhi(g.z); a[2] = u * vv + a[2];
    u.x = bflo(g.w); u.y = bfhi(g.w); a[3] = u * vv + a[3];
}

template<int MODE>
__global__ __launch_bounds__(256) void spmm_kernel(SpmmG4 Gd)
{
    int blk = blockIdx.x;
    int gi = (blk >= Gd.g[1].blkBase) + (blk >= Gd.g[2].blkBase)
           + (blk >= Gd.g[3].blkBase);
    const SpmmG E = Gd.g[gi];
    int row = (blk - E.blkBase) * 4 + (threadIdx.x >> 6);
    if (row >= E.n_dst) return;
    int lane = threadIdx.x & 63;
    int q   = lane >> 4;     // quarter 0..3 -> edge j+q
    int l16 = lane & 15;     // elems l16*8 .. l16*8+7

    int sO = E.off[row], eO = E.off[row + 1];
    vfloat2 acc2[4];
    #pragma unroll
    for (int k = 0; k < 4; ++k) { acc2[k].x = 0.f; acc2[k].y = 0.f; }

    const int2* pp = E.pairs + sO;
    int nfull = (eO - sO) >> 3;       // full 8-edge pipeline iterations

    // pipeline state: P = iter i pairs, Q = iter i+1 pairs; G = iter i rows
    int2 Pa, Pb, Qa, Qb;
    uint4 Ga, Gb, Ha, Hb;
    if (nfull >= 1) { Pa = ldp_nt(pp + q); Pb = ldp_nt(pp + 4 + q); }
    if (nfull >= 2) { Qa = ldp_nt(pp + 8 + q); Qb = ldp_nt(pp + 12 + q); }
    if (nfull >= 1) { Ga = grow(E.x, Pa.x, l16); Gb = grow(E.x, Pb.x, l16); }

    for (int i = 0; i + 2 < nfull; ++i) {       // steady state, no branches
        int base = (i + 2) << 3;
        int2 Ra = ldp_nt(pp + base + q);        // pairs 2 ahead
        int2 Rb = ldp_nt(pp + base + 4 + q);
        Ha = grow(E.x, Qa.x, l16);              // rows 1 ahead
        Hb = grow(E.x, Qb.x, l16);
        fma8(acc2, Ga, __int_as_float(Pa.y));
        fma8(acc2, Gb, __int_as_float(Pb.y));
        Pa = Qa; Pb = Qb; Qa = Ra; Qb = Rb; Ga = Ha; Gb = Hb;
    }
    if (nfull >= 2) {                           // drain: one staged iter left
        Ha = grow(E.x, Qa.x, l16);
        Hb = grow(E.x, Qb.x, l16);
        fma8(acc2, Ga, __int_as_float(Pa.y));
        fma8(acc2, Gb, __int_as_float(Pb.y));
        Pa = Qa; Pb = Qb; Ga = Ha; Gb = Hb;
    }
    if (nfull >= 1) {
        fma8(acc2, Ga, __int_as_float(Pa.y));
        fma8(acc2, Gb, __int_as_float(Pb.y));
    }
    for (int j = sO + (nfull << 3); j < eO; j += 4) {   // predicated tail quad
        if (j + q < eO) {
            int2 p = ldp_nt(E.pairs + j + q);
            uint4 g = grow(E.x, p.x, l16);
            fma8(acc2, g, __int_as_float(p.y));
        }
    }

    float acc[8] = { acc2[0].x, acc2[0].y, acc2[1].x, acc2[1].y,
                     acc2[2].x, acc2[2].y, acc2[3].x, acc2[3].y };
    #pragma unroll
    for (int k = 0; k < 8; ++k) {          // combine 4 quarter partials
        acc[k] += __shfl_xor(acc[k], 16);
        acc[k] += __shfl_xor(acc[k], 32);
    }
    if (q != 0) return;
    long rb = (long)row << 7;
    if (MODE != 3) {
        uint4 o;
        o.x = f2bf(acc[0]) | (f2bf(acc[1]) << 16);
        o.y = f2bf(acc[2]) | (f2bf(acc[3]) << 16);
        o.z = f2bf(acc[4]) | (f2bf(acc[5]) << 16);
        o.w = f2bf(acc[6]) | (f2bf(acc[7]) << 16);
        ((uint4*)(E.y + rb))[l16] = o;
    }
    if (MODE == 1) {
        const float4* ap = (const float4*)(E.aux + rb) + l16 * 2;
        float4* op = (float4*)(E.out + rb) + l16 * 2;
        float4 a0 = ap[0], a1 = ap[1];
        a0.x += acc[0]; a0.y += acc[1]; a0.z += acc[2]; a0.w += acc[3];
        a1.x += acc[4]; a1.y += acc[5]; a1.z += acc[6]; a1.w += acc[7];
        op[0] = a0; op[1] = a1;
    } else if (MODE == 2) {
        float4* op = (float4*)(E.out + rb) + l16 * 2;
        float4 a0 = op[0], a1 = op[1];
        a0.x += acc[0]; a0.y += acc[1]; a0.z += acc[2]; a0.w += acc[3];
        a1.x += acc[4]; a1.y += acc[5]; a1.z += acc[6]; a1.w += acc[7];
        op[0] = a0; op[1] = a1;
    } else if (MODE == 3) {
        float4* op = (float4*)(E.out + rb) + l16 * 2;
        float4 a0 = op[0], a1 = op[1];
        a0.x = (a0.x + acc[0]) * 0.25f; a0.y = (a0.y + acc[1]) * 0.25f;
        a0.z = (a0.z + acc[2]) * 0.25f; a0.w = (a0.w + acc[3]) * 0.25f;
        a1.x = (a1.x + acc[4]) * 0.25f; a1.y = (a1.y + acc[5]) * 0.25f;
        a1.z = (a1.z + acc[6]) * 0.25f; a1.w = (a1.w + acc[7]) * 0.25f;
        op[0] = a0; op[1] = a1;
    }
}

extern "C" void kernel_launch(void* const* d_in, const int* in_sizes, int n_in,
                              void* d_out, int out_size, void* d_ws, size_t ws_size,
                              hipStream_t stream)
{
    static const int Ns[4] = {100000, 40000, 20000, 10000};
    static const int Ps[4] = { 40000, 100000, 100000, 40000};
    const int maxN = 100000, maxP = 100000;

    int nnz[4];
    for (int g = 0; g < 4; ++g) nnz[g] = in_sizes[4 + g];

    // wshift: largest span (pow2, <=512) with expected edges <= 5120/bucket
    auto calc_ws = [](int n, int m) {
        int ws = 0;
        while (ws < 9 && (double)m * (double)(1 << (ws + 1)) <= 5120.0 * n) ++ws;
        while (((n + (1 << ws) - 1) >> ws) > MAX_NB) ++ws;
        return ws;
    };

    // ---- stream geometry (pointer-free) ----
    B8 G;
    int cbase = 0, pbTot = 0;
    for (int g = 0; g < 4; ++g)
        for (int dir = 0; dir < 2; ++dir) {
            BStream& s = G.s[2 * g + dir];
            s.nnz = nnz[g];
            s.n   = dir ? Ns[g] : Ps[g];
            s.wshift = calc_ws(s.n, s.nnz);
            s.nb = (s.n + (1 << s.wshift) - 1) >> s.wshift;
            s.cbase = cbase;
            G.pb[2 * g + dir] = pbTot;
            cbase += s.nb + 1;
            pbTot += s.nb;
        }

    // ---- can we afford per-graph cur/t buffers? ----
    auto padded = [](size_t b) { return (b + 255) & ~(size_t)255; };
    size_t need = 0;
    for (int g = 0; g < 4; ++g) need += padded((size_t)Ns[g] * D * 2)
                                      + padded((size_t)Ps[g] * D * 2);
    for (int g = 0; g < 4; ++g) need += padded((size_t)(Ps[g] + 1) * 4)
                                      + padded((size_t)(Ns[g] + 1) * 4);
    for (int g = 0; g < 4; ++g) need += 2 * padded((size_t)nnz[g] * 8);
    need += padded((size_t)cbase * NC * 4) + padded((size_t)cbase * 4);
    bool perGraph = need <= ws_size;

    // ---- workspace carve ----
    char* wp = (char*)d_ws;
    auto alloc = [&](size_t bytes) -> void* {
        void* p = (void*)wp; wp += (bytes + 255) & ~(size_t)255; return p;
    };
    unsigned short* curG[4]; unsigned short* tG[4];
    if (perGraph) {
        for (int g = 0; g < 4; ++g) {
            curG[g] = (unsigned short*)alloc((size_t)Ns[g] * D * 2);
            tG[g]   = (unsigned short*)alloc((size_t)Ps[g] * D * 2);
        }
    } else {
        unsigned short* cur = (unsigned short*)alloc((size_t)maxN * D * 2);
        unsigned short* t   = (unsigned short*)alloc((size_t)maxP * D * 2);
        for (int g = 0; g < 4; ++g) { curG[g] = cur; tG[g] = t; }
    }
    int* offP[4]; int* offN[4]; int2* pairsP[4]; int2* pairsN[4];
    for (int g = 0; g < 4; ++g) {
        offP[g] = (int*)alloc((size_t)(Ps[g] + 1) * sizeof(int));
        offN[g] = (int*)alloc((size_t)(Ns[g] + 1) * sizeof(int));
    }
    for (int g = 0; g < 4; ++g) {
        pairsP[g] = (int2*)alloc((size_t)nnz[g] * sizeof(int2));
        pairsN[g] = (int2*)alloc((size_t)nnz[g] * sizeof(int2));
    }
    G.cnt = (int*)alloc((size_t)cbase * NC * sizeof(int));
    G.gBB = (int*)alloc((size_t)cbase * sizeof(int));

    // staged packed int2 -> d_out (fully consumed by permute before spmm)
    int2* stagedBase = (int2*)d_out;
    size_t soff = 0;
    for (int g = 0; g < 4; ++g)
        for (int dir = 0; dir < 2; ++dir) {
            BStream& s = G.s[2 * g + dir];
            s.dst  = (const int*)d_in[8 + 2 * g + (dir ? 1 : 0)];
            s.src  = (const int*)d_in[8 + 2 * g + (dir ? 0 : 1)];
            s.vals = (const float*)d_in[4 + g];
            s.off  = dir ? offN[g] : offP[g];
            s.pairs = dir ? pairsN[g] : pairsP[g];
            s.staged = stagedBase + soff;
            soff += (size_t)nnz[g];
        }

    // ---- CSR build: count -> scan -> partition -> permute ----
    countB_kernel<<<dim3(NC, 8), 512, 0, stream>>>(G);
    scanB_kernel<<<8, 512, 0, stream>>>(G);
    partition_kernel<<<dim3(NC, 8), 512, 0, stream>>>(G);
    permute_kernel<<<pbTot, 512, 0, stream>>>(G);

    // ---- propagation ----
    size_t out_off[4]; size_t oo = 0;
    for (int g = 0; g < 4; ++g) { out_off[g] = oo; oo += (size_t)Ns[g] * D; }

    if (perGraph) {
        // one cvt dispatch, then 2 fused spmm dispatches per layer
        CvtG4 C; int cb = 0;
        for (int g = 0; g < 4; ++g) {
            int n8 = Ns[g] * D / 8;
            C.c[g] = { (const float*)d_in[g], (uint4*)curG[g], n8, cb };
            cb += (n8 + 255) / 256;
        }
        cvt_bf16_kernel<<<cb, 256, 0, stream>>>(C);

        SpmmG4 TP, TN;
        int pb = 0, nb = 0;
        for (int g = 0; g < 4; ++g) {
            TP.g[g] = { curG[g], tG[g], nullptr, nullptr,
                        offP[g], pairsP[g], Ps[g], pb };
            pb += (Ps[g] + 3) / 4;
            TN.g[g] = { tG[g], curG[g], (float*)d_out + out_off[g],
                        (const float*)d_in[g], offN[g], pairsN[g], Ns[g], nb };
            nb += (Ns[g] + 3) / 4;
        }
        spmm_kernel<0><<<pb, 256, 0, stream>>>(TP);
        spmm_kernel<1><<<nb, 256, 0, stream>>>(TN);
        spmm_kernel<0><<<pb, 256, 0, stream>>>(TP);
        spmm_kernel<2><<<nb, 256, 0, stream>>>(TN);
        spmm_kernel<0><<<pb, 256, 0, stream>>>(TP);
        spmm_kernel<3><<<nb, 256, 0, stream>>>(TN);
    } else {
        // shared-buffer fallback: per-graph sequential, 1-entry tables
        const int BIG = 0x7FFFFFFF;
        for (int g = 0; g < 4; ++g) {
            const float* emb = (const float*)d_in[g];
            float* outg = (float*)d_out + out_off[g];
            const int N = Ns[g], P = Ps[g];
            int n8 = N * D / 8;
            CvtG4 C;
            C.c[0] = { emb, (uint4*)curG[g], n8, 0 };
            for (int i = 1; i < 4; ++i) C.c[i].blkBase = BIG;
            cvt_bf16_kernel<<<(n8 + 255) / 256, 256, 0, stream>>>(C);

            SpmmG4 TP, TN;
            TP.g[0] = { curG[g], tG[g], nullptr, nullptr,
                        offP[g], pairsP[g], P, 0 };
            TN.g[0] = { tG[g], curG[g], outg, emb, offN[g], pairsN[g], N, 0 };
            for (int i = 1; i < 4; ++i) { TP.g[i].blkBase = BIG; TN.g[i].blkBase = BIG; }
            int gp = (P + 3) / 4, gn = (N + 3) / 4;
            spmm_kernel<0><<<gp, 256, 0, stream>>>(TP);
            spmm_kernel<1><<<gn, 256, 0, stream>>>(TN);
            spmm_kernel<0><<<gp, 256, 0, stream>>>(TP);
            spmm_kernel<2><<<gn, 256, 0, stream>>>(TN);
            spmm_kernel<0><<<gp, 256, 0, stream>>>(TP);
            spmm_kernel<3><<<gn, 256, 0, stream>>>(TN);
        }
    }
}

// Round 7
// 1259.114 us; speedup vs baseline: 1.0828x; 1.0828x over previous
//
#include <hip/hip_runtime.h>

// ---------------------------------------------------------------------------
// LightGCN-style propagation, 4 independent bipartite graphs.
// R10: R9 post-mortem -> revert spmm software pipelining (null on dispatch,
// net regression: HW vmcnt scoreboarding already gives MLP; nt pair loads
// raised FETCH). New lever: the spmm is throughput-capped at ~3.7 TB/s on
// L3-resident random gathers, so cut bytes in the accumulator chain:
//   - MODE1 reads emb from cur (bf16, 43.5MB) instead of aux fp32 (87MB);
//   - running sum kept bf16 across layers (MODE1 w 43.5, MODE2 rw 87,
//     MODE3 r 43.5 + final fp32 write) instead of fp32 (87/174/87+87).
//   -217MB of ~3.56GB spmm traffic. ws-guarded; fp32 fallback modes 4/5/6.
// Build (R6-R8b): countB -> scanB -> partition (packed (src|dl<<17,val)) ->
// permute (per-bucket LDS counting sort -> CSR off[] + pairs), all
// coalesced, no global atomics. Fused multi-graph dispatches via desc tables.
// ---------------------------------------------------------------------------

#define D 128
#define NC 64          // partition chunks per stream
#define TILE_CAP 7168  // permute LDS tile capacity (edges)
#define MAX_NB 512     // max dest-buckets per stream

// native clang vectors (accepted by __builtin_nontemporal_load)
typedef int   vint4   __attribute__((ext_vector_type(4)));
typedef float vfloat4 __attribute__((ext_vector_type(4)));

// ---- bf16 helpers (RNE pack, bit-shift unpack) ----
__device__ __forceinline__ unsigned f2bf(float f) {
    unsigned u = __float_as_uint(f);
    u += 0x7FFFu + ((u >> 16) & 1u);
    return u >> 16;
}
__device__ __forceinline__ float bflo(unsigned u) { return __uint_as_float(u << 16); }
__device__ __forceinline__ float bfhi(unsigned u) { return __uint_as_float(u & 0xFFFF0000u); }

// ---- fp32 -> bf16 row conversion, fused over graphs ----
struct CvtG { const float* x; uint4* y; int n8, blkBase; };
struct CvtG4 { CvtG c[4]; };

__global__ __launch_bounds__(256) void cvt_bf16_kernel(CvtG4 Cd)
{
    int blk = blockIdx.x;
    int gi = (blk >= Cd.c[1].blkBase) + (blk >= Cd.c[2].blkBase)
           + (blk >= Cd.c[3].blkBase);
    const CvtG E = Cd.c[gi];
    int i = (blk - E.blkBase) * 256 + threadIdx.x;
    if (i >= E.n8) return;
    const float4* xp = (const float4*)E.x + (size_t)i * 2;
    float4 a = xp[0], b = xp[1];
    uint4 o;
    o.x = f2bf(a.x) | (f2bf(a.y) << 16);
    o.y = f2bf(a.z) | (f2bf(a.w) << 16);
    o.z = f2bf(b.x) | (f2bf(b.y) << 16);
    o.w = f2bf(b.z) | (f2bf(b.w) << 16);
    E.y[i] = o;
}

// ---- per-(graph,dir) stream descriptor ----
struct BStream {
    const int* dst; const int* src; const float* vals;
    int2* staged;        // K3 output (src|dl<<17, val), bucket-major (d_out)
    int2* pairs;         // final CSR pairs
    int* off;            // final CSR offsets [n+1]
    int nnz, n, wshift, nb, cbase;
};
struct B8 {
    BStream s[8];
    int* cnt;            // [sum(nb+1)][NC]: counts -> cursor starts (K2 rewrite)
    int* gBB;            // [sum(nb+1)]: bucket bases + per-stream sentinel
    int pb[8];           // permute-block base per stream
};

// ---- K1: coarse bucket histogram, one dst pass (nt streaming reads) ----
__global__ __launch_bounds__(512) void countB_kernel(B8 G)
{
    const BStream S = G.s[blockIdx.y];
    int c = blockIdx.x;
    __shared__ int h[MAX_NB];
    for (int i = threadIdx.x; i < S.nb; i += 512) h[i] = 0;
    __syncthreads();
    int len = (((S.nnz + NC - 1) / NC) + 3) & ~3;
    int e0 = c * len, e1 = min(S.nnz, e0 + len);
    if (e0 < e1) {
        int nq = (e1 - e0) >> 2;
        const vint4* dq = (const vint4*)(S.dst + e0);
        for (int i = threadIdx.x; i < nq; i += 512) {
            vint4 v = __builtin_nontemporal_load(&dq[i]);
            atomicAdd(&h[v.x >> S.wshift], 1);
            atomicAdd(&h[v.y >> S.wshift], 1);
            atomicAdd(&h[v.z >> S.wshift], 1);
            atomicAdd(&h[v.w >> S.wshift], 1);
        }
        for (int e = e0 + (nq << 2) + (int)threadIdx.x; e < e1; e += 512)
            atomicAdd(&h[S.dst[e] >> S.wshift], 1);
    }
    __syncthreads();
    int* out = G.cnt + (size_t)S.cbase * NC;
    for (int i = threadIdx.x; i < S.nb; i += 512) out[(size_t)i * NC + c] = h[i];
}

// ---- K2: bucket totals + exscan -> bases and per-chunk cursor starts ----
__global__ __launch_bounds__(512) void scanB_kernel(B8 G)
{
    const BStream S = G.s[blockIdx.x];
    int* cnt = G.cnt + (size_t)S.cbase * NC;
    int* bb  = G.gBB + S.cbase;
    __shared__ int wsum[8];
    int b = threadIdx.x;
    int t = 0;
    if (b < S.nb) {
        int* row = cnt + (size_t)b * NC;
        int run = 0;
        #pragma unroll
        for (int c = 0; c < NC; ++c) { int v = row[c]; row[c] = run; run += v; }
        t = run;
    }
    int lane = b & 63, w = b >> 6;
    int x = t;
    #pragma unroll
    for (int s = 1; s < 64; s <<= 1) {
        int y = __shfl_up(x, s, 64);
        if (lane >= s) x += y;
    }
    if (lane == 63) wsum[w] = x;
    __syncthreads();
    if (b == 0) {
        int run = 0;
        #pragma unroll
        for (int i = 0; i < 8; ++i) { int v = wsum[i]; wsum[i] = run; run += v; }
    }
    __syncthreads();
    int excl = wsum[w] + x - t;
    if (b < S.nb) {
        bb[b] = excl;
        int* row = cnt + (size_t)b * NC;
        #pragma unroll
        for (int c = 0; c < NC; ++c) row[c] += excl;
    }
    if (b == 0) { bb[S.nb] = S.nnz; S.off[S.n] = S.nnz; }
}

// ---- K3: partition edges bucket-major, packed (src|dl<<17, val) ----
__global__ __launch_bounds__(512) void partition_kernel(B8 G)
{
    const BStream S = G.s[blockIdx.y];
    int c = blockIdx.x;
    __shared__ int cur[MAX_NB];
    const int* cs = G.cnt + (size_t)S.cbase * NC;
    for (int i = threadIdx.x; i < S.nb; i += 512) cur[i] = cs[(size_t)i * NC + c];
    __syncthreads();
    int len = (((S.nnz + NC - 1) / NC) + 3) & ~3;
    int e0 = c * len, e1 = min(S.nnz, e0 + len);
    if (e0 >= e1) return;
    int smask = (1 << S.wshift) - 1;
    int nq = (e1 - e0) >> 2;
    const vint4*   dq = (const vint4*)(S.dst + e0);
    const vint4*   sq = (const vint4*)(S.src + e0);
    const vfloat4* vq = (const vfloat4*)(S.vals + e0);
    for (int i = threadIdx.x; i < nq; i += 512) {
        vint4 dv = __builtin_nontemporal_load(&dq[i]);
        vint4 sv = __builtin_nontemporal_load(&sq[i]);
        vfloat4 vv = __builtin_nontemporal_load(&vq[i]);
        int p;
        p = atomicAdd(&cur[dv.x >> S.wshift], 1);
        S.staged[p] = make_int2(sv.x | ((dv.x & smask) << 17), __float_as_int(vv.x));
        p = atomicAdd(&cur[dv.y >> S.wshift], 1);
        S.staged[p] = make_int2(sv.y | ((dv.y & smask) << 17), __float_as_int(vv.y));
        p = atomicAdd(&cur[dv.z >> S.wshift], 1);
        S.staged[p] = make_int2(sv.z | ((dv.z & smask) << 17), __float_as_int(vv.z));
        p = atomicAdd(&cur[dv.w >> S.wshift], 1);
        S.staged[p] = make_int2(sv.w | ((dv.w & smask) << 17), __float_as_int(vv.w));
    }
    for (int e = e0 + (nq << 2) + (int)threadIdx.x; e < e1; e += 512) {
        int d = S.dst[e];
        int p = atomicAdd(&cur[d >> S.wshift], 1);
        S.staged[p] = make_int2(S.src[e] | ((d & smask) << 17), __float_as_int(S.vals[e]));
    }
}

// ---- K4: per-bucket dest-sort through LDS; writes CSR off[] + pairs ----
__global__ __launch_bounds__(512) void permute_kernel(B8 G)
{
    int gb = blockIdx.x;
    int s = 0;
    #pragma unroll
    for (int i = 1; i < 8; ++i) s += (gb >= G.pb[i]);
    const BStream S = G.s[s];
    int b = gb - G.pb[s];
    const int* bb = G.gBB + S.cbase;
    int B0 = bb[b], B1 = bb[b + 1];
    int cnt = B1 - B0;
    int span = 1 << S.wshift;
    int dbase = b << S.wshift;

    __shared__ int2 tile[TILE_CAP];
    __shared__ int cursor[MAX_NB];
    __shared__ int wsum[8];
    int tid = threadIdx.x;

    for (int i = tid; i < span; i += 512) cursor[i] = 0;
    __syncthreads();
    for (int i = B0 + tid; i < B1; i += 512)
        atomicAdd(&cursor[((unsigned)S.staged[i].x) >> 17], 1);
    __syncthreads();

    // exclusive scan over span (<=512) counts
    int v = (tid < span) ? cursor[tid] : 0;
    int lane = tid & 63, w = tid >> 6;
    int x = v;
    #pragma unroll
    for (int st = 1; st < 64; st <<= 1) {
        int y = __shfl_up(x, st, 64);
        if (lane >= st) x += y;
    }
    if (lane == 63) wsum[w] = x;
    __syncthreads();
    if (tid == 0) {
        int run = 0;
        #pragma unroll
        for (int i = 0; i < 8; ++i) { int t = wsum[i]; wsum[i] = run; run += t; }
    }
    __syncthreads();
    int excl = wsum[w] + x - v;
    __syncthreads();
    if (tid < span) {
        int d = dbase + tid;
        if (d < S.n) S.off[d] = B0 + excl;
        cursor[tid] = excl;
    }
    __syncthreads();

    if (cnt <= TILE_CAP) {
        for (int i = B0 + tid; i < B1; i += 512) {
            int2 pe = S.staged[i];
            int dl = ((unsigned)pe.x) >> 17;
            int p = atomicAdd(&cursor[dl], 1);
            tile[p] = make_int2(pe.x & 0x1FFFF, pe.y);
        }
        __syncthreads();
        for (int i = tid; i < cnt; i += 512) S.pairs[B0 + i] = tile[i];
    } else {
        // statistically-never fallback; staged != pairs so no in-place hazard
        for (int i = B0 + tid; i < B1; i += 512) {
            int2 pe = S.staged[i];
            int dl = ((unsigned)pe.x) >> 17;
            int p = atomicAdd(&cursor[dl], 1);
            S.pairs[B0 + p] = make_int2(pe.x & 0x1FFFF, pe.y);
        }
    }
}

// ---- gather SpMM, fused over graphs via desc table ----
// bf16-accumulator modes (ob = bf16 running sum buffer):
//   MODE 0: y = acc                         (P-side -> t)
//   MODE 1: y = acc; ob = y_old(embbf)+acc  (N l1; y held emb_bf)
//   MODE 2: y = acc; ob += acc              (N l2)
//   MODE 3: out = (ob + acc) * 0.25         (N l3, fp32 final)
// fp32 fallback modes:
//   MODE 4: y = acc; out = aux + acc
//   MODE 5: y = acc; out += acc
//   MODE 6: out = (out + acc) * 0.25
struct SpmmG {
    const unsigned short* x;   // bf16 [n_src][128]
    unsigned short* y;         // bf16 [n_dst][128]
    unsigned short* ob;        // bf16 running sum [n_dst][128]
    float* out;                // fp32 [n_dst][128]
    const float* aux;          // fp32 emb (MODE 4)
    const int* off; const int2* pairs;
    int n_dst, blkBase;
};
struct SpmmG4 { SpmmG g[4]; };

template<int MODE>
__global__ __launch_bounds__(256) void spmm_kernel(SpmmG4 Gd)
{
    int blk = blockIdx.x;
    int gi = (blk >= Gd.g[1].blkBase) + (blk >= Gd.g[2].blkBase)
           + (blk >= Gd.g[3].blkBase);
    const SpmmG E = Gd.g[gi];
    int row = (blk - E.blkBase) * 4 + (threadIdx.x >> 6);
    if (row >= E.n_dst) return;
    int lane = threadIdx.x & 63;
    int q   = lane >> 4;     // quarter 0..3 -> edge j+q
    int l16 = lane & 15;     // elems l16*8 .. l16*8+7

    int s = E.off[row], e = E.off[row + 1];
    float acc[8] = {0.f,0.f,0.f,0.f,0.f,0.f,0.f,0.f};

    int j = s;
    for (; j + 7 < e; j += 8) {            // 8 edges/iter, all valid
        int2 p0 = E.pairs[j + q];
        int2 p1 = E.pairs[j + 4 + q];
        float v0 = __int_as_float(p0.y);
        float v1 = __int_as_float(p1.y);
        uint4 g0 = ((const uint4*)(E.x + ((long)p0.x << 7)))[l16];
        uint4 g1 = ((const uint4*)(E.x + ((long)p1.x << 7)))[l16];
        acc[0] += v0 * bflo(g0.x); acc[1] += v0 * bfhi(g0.x);
        acc[2] += v0 * bflo(g0.y); acc[3] += v0 * bfhi(g0.y);
        acc[4] += v0 * bflo(g0.z); acc[5] += v0 * bfhi(g0.z);
        acc[6] += v0 * bflo(g0.w); acc[7] += v0 * bfhi(g0.w);
        acc[0] += v1 * bflo(g1.x); acc[1] += v1 * bfhi(g1.x);
        acc[2] += v1 * bflo(g1.y); acc[3] += v1 * bfhi(g1.y);
        acc[4] += v1 * bflo(g1.z); acc[5] += v1 * bfhi(g1.z);
        acc[6] += v1 * bflo(g1.w); acc[7] += v1 * bfhi(g1.w);
    }
    for (; j < e; j += 4) {                // predicated tail quad
        if (j + q < e) {
            int2 p = E.pairs[j + q];
            float v = __int_as_float(p.y);
            uint4 g = ((const uint4*)(E.x + ((long)p.x << 7)))[l16];
            acc[0] += v * bflo(g.x); acc[1] += v * bfhi(g.x);
            acc[2] += v * bflo(g.y); acc[3] += v * bfhi(g.y);
            acc[4] += v * bflo(g.z); acc[5] += v * bfhi(g.z);
            acc[6] += v * bflo(g.w); acc[7] += v * bfhi(g.w);
        }
    }
    #pragma unroll
    for (int k = 0; k < 8; ++k) {          // combine 4 quarter partials
        acc[k] += __shfl_xor(acc[k], 16);
        acc[k] += __shfl_xor(acc[k], 32);
    }
    if (q != 0) return;
    long rb = (long)row << 7;

    uint4 prev;                            // bf16 row read before y overwrite
    if (MODE == 1) prev = ((const uint4*)(E.y + rb))[l16];
    if (MODE == 2 || MODE == 3) prev = ((const uint4*)(E.ob + rb))[l16];

    if (MODE != 3 && MODE != 6) {
        uint4 o;
        o.x = f2bf(acc[0]) | (f2bf(acc[1]) << 16);
        o.y = f2bf(acc[2]) | (f2bf(acc[3]) << 16);
        o.z = f2bf(acc[4]) | (f2bf(acc[5]) << 16);
        o.w = f2bf(acc[6]) | (f2bf(acc[7]) << 16);
        ((uint4*)(E.y + rb))[l16] = o;
    }
    if (MODE == 1 || MODE == 2) {
        float b0 = acc[0] + bflo(prev.x), b1 = acc[1] + bfhi(prev.x);
        float b2 = acc[2] + bflo(prev.y), b3 = acc[3] + bfhi(prev.y);
        float b4 = acc[4] + bflo(prev.z), b5 = acc[5] + bfhi(prev.z);
        float b6 = acc[6] + bflo(prev.w), b7 = acc[7] + bfhi(prev.w);
        uint4 o;
        o.x = f2bf(b0) | (f2bf(b1) << 16);
        o.y = f2bf(b2) | (f2bf(b3) << 16);
        o.z = f2bf(b4) | (f2bf(b5) << 16);
        o.w = f2bf(b6) | (f2bf(b7) << 16);
        ((uint4*)(E.ob + rb))[l16] = o;
    } else if (MODE == 3) {
        float4* op = (float4*)(E.out + rb) + l16 * 2;
        float4 a0, a1;
        a0.x = (acc[0] + bflo(prev.x)) * 0.25f; a0.y = (acc[1] + bfhi(prev.x)) * 0.25f;
        a0.z = (acc[2] + bflo(prev.y)) * 0.25f; a0.w = (acc[3] + bfhi(prev.y)) * 0.25f;
        a1.x = (acc[4] + bflo(prev.z)) * 0.25f; a1.y = (acc[5] + bfhi(prev.z)) * 0.25f;
        a1.z = (acc[6] + bflo(prev.w)) * 0.25f; a1.w = (acc[7] + bfhi(prev.w)) * 0.25f;
        op[0] = a0; op[1] = a1;
    } else if (MODE == 4) {
        const float4* ap = (const float4*)(E.aux + rb) + l16 * 2;
        float4* op = (float4*)(E.out + rb) + l16 * 2;
        float4 a0 = ap[0], a1 = ap[1];
        a0.x += acc[0]; a0.y += acc[1]; a0.z += acc[2]; a0.w += acc[3];
        a1.x += acc[4]; a1.y += acc[5]; a1.z += acc[6]; a1.w += acc[7];
        op[0] = a0; op[1] = a1;
    } else if (MODE == 5) {
        float4* op = (float4*)(E.out + rb) + l16 * 2;
        float4 a0 = op[0], a1 = op[1];
        a0.x += acc[0]; a0.y += acc[1]; a0.z += acc[2]; a0.w += acc[3];
        a1.x += acc[4]; a1.y += acc[5]; a1.z += acc[6]; a1.w += acc[7];
        op[0] = a0; op[1] = a1;
    } else if (MODE == 6) {
        float4* op = (float4*)(E.out + rb) + l16 * 2;
        float4 a0 = op[0], a1 = op[1];
        a0.x = (a0.x + acc[0]) * 0.25f; a0.y = (a0.y + acc[1]) * 0.25f;
        a0.z = (a0.z + acc[2]) * 0.25f; a0.w = (a0.w + acc[3]) * 0.25f;
        a1.x = (a1.x + acc[4]) * 0.25f; a1.y = (a1.y + acc[5]) * 0.25f;
        a1.z = (a1.z + acc[6]) * 0.25f; a1.w = (a1.w + acc[7]) * 0.25f;
        op[0] = a0; op[1] = a1;
    }
}

extern "C" void kernel_launch(void* const* d_in, const int* in_sizes, int n_in,
                              void* d_out, int out_size, void* d_ws, size_t ws_size,
                              hipStream_t stream)
{
    static const int Ns[4] = {100000, 40000, 20000, 10000};
    static const int Ps[4] = { 40000, 100000, 100000, 40000};
    const int maxN = 100000, maxP = 100000;

    int nnz[4];
    for (int g = 0; g < 4; ++g) nnz[g] = in_sizes[4 + g];

    // wshift: largest span (pow2, <=512) with expected edges <= 5120/bucket
    auto calc_ws = [](int n, int m) {
        int ws = 0;
        while (ws < 9 && (double)m * (double)(1 << (ws + 1)) <= 5120.0 * n) ++ws;
        while (((n + (1 << ws) - 1) >> ws) > MAX_NB) ++ws;
        return ws;
    };

    // ---- stream geometry (pointer-free) ----
    B8 G;
    int cbase = 0, pbTot = 0;
    for (int g = 0; g < 4; ++g)
        for (int dir = 0; dir < 2; ++dir) {
            BStream& s = G.s[2 * g + dir];
            s.nnz = nnz[g];
            s.n   = dir ? Ns[g] : Ps[g];
            s.wshift = calc_ws(s.n, s.nnz);
            s.nb = (s.n + (1 << s.wshift) - 1) >> s.wshift;
            s.cbase = cbase;
            G.pb[2 * g + dir] = pbTot;
            cbase += s.nb + 1;
            pbTot += s.nb;
        }

    // ---- ws budgets: perGraph cur/t; +ob (bf16 running sum) ----
    auto padded = [](size_t b) { return (b + 255) & ~(size_t)255; };
    size_t need = 0;
    for (int g = 0; g < 4; ++g) need += padded((size_t)Ns[g] * D * 2)
                                      + padded((size_t)Ps[g] * D * 2);
    for (int g = 0; g < 4; ++g) need += padded((size_t)(Ps[g] + 1) * 4)
                                      + padded((size_t)(Ns[g] + 1) * 4);
    for (int g = 0; g < 4; ++g) need += 2 * padded((size_t)nnz[g] * 8);
    need += padded((size_t)cbase * NC * 4) + padded((size_t)cbase * 4);
    size_t needOB = need;
    for (int g = 0; g < 4; ++g) needOB += padded((size_t)Ns[g] * D * 2);
    bool perGraph = need <= ws_size;
    bool useOB = needOB <= ws_size;

    // ---- workspace carve ----
    char* wp = (char*)d_ws;
    auto alloc = [&](size_t bytes) -> void* {
        void* p = (void*)wp; wp += (bytes + 255) & ~(size_t)255; return p;
    };
    unsigned short* curG[4]; unsigned short* tG[4]; unsigned short* obG[4];
    if (perGraph) {
        for (int g = 0; g < 4; ++g) {
            curG[g] = (unsigned short*)alloc((size_t)Ns[g] * D * 2);
            tG[g]   = (unsigned short*)alloc((size_t)Ps[g] * D * 2);
        }
    } else {
        unsigned short* cur = (unsigned short*)alloc((size_t)maxN * D * 2);
        unsigned short* t   = (unsigned short*)alloc((size_t)maxP * D * 2);
        for (int g = 0; g < 4; ++g) { curG[g] = cur; tG[g] = t; }
    }
    int* offP[4]; int* offN[4]; int2* pairsP[4]; int2* pairsN[4];
    for (int g = 0; g < 4; ++g) {
        offP[g] = (int*)alloc((size_t)(Ps[g] + 1) * sizeof(int));
        offN[g] = (int*)alloc((size_t)(Ns[g] + 1) * sizeof(int));
    }
    for (int g = 0; g < 4; ++g) {
        pairsP[g] = (int2*)alloc((size_t)nnz[g] * sizeof(int2));
        pairsN[g] = (int2*)alloc((size_t)nnz[g] * sizeof(int2));
    }
    G.cnt = (int*)alloc((size_t)cbase * NC * sizeof(int));
    G.gBB = (int*)alloc((size_t)cbase * sizeof(int));
    if (useOB)
        for (int g = 0; g < 4; ++g)
            obG[g] = (unsigned short*)alloc((size_t)Ns[g] * D * 2);
    else
        for (int g = 0; g < 4; ++g) obG[g] = nullptr;

    // staged packed int2 -> d_out (fully consumed by permute before spmm)
    int2* stagedBase = (int2*)d_out;
    size_t soff = 0;
    for (int g = 0; g < 4; ++g)
        for (int dir = 0; dir < 2; ++dir) {
            BStream& s = G.s[2 * g + dir];
            s.dst  = (const int*)d_in[8 + 2 * g + (dir ? 1 : 0)];
            s.src  = (const int*)d_in[8 + 2 * g + (dir ? 0 : 1)];
            s.vals = (const float*)d_in[4 + g];
            s.off  = dir ? offN[g] : offP[g];
            s.pairs = dir ? pairsN[g] : pairsP[g];
            s.staged = stagedBase + soff;
            soff += (size_t)nnz[g];
        }

    // ---- CSR build: count -> scan -> partition -> permute ----
    countB_kernel<<<dim3(NC, 8), 512, 0, stream>>>(G);
    scanB_kernel<<<8, 512, 0, stream>>>(G);
    partition_kernel<<<dim3(NC, 8), 512, 0, stream>>>(G);
    permute_kernel<<<pbTot, 512, 0, stream>>>(G);

    // ---- propagation ----
    size_t out_off[4]; size_t oo = 0;
    for (int g = 0; g < 4; ++g) { out_off[g] = oo; oo += (size_t)Ns[g] * D; }

    if (perGraph) {
        // one cvt dispatch, then 2 fused spmm dispatches per layer
        CvtG4 C; int cb = 0;
        for (int g = 0; g < 4; ++g) {
            int n8 = Ns[g] * D / 8;
            C.c[g] = { (const float*)d_in[g], (uint4*)curG[g], n8, cb };
            cb += (n8 + 255) / 256;
        }
        cvt_bf16_kernel<<<cb, 256, 0, stream>>>(C);

        SpmmG4 TP, TN;
        int pb = 0, nb = 0;
        for (int g = 0; g < 4; ++g) {
            TP.g[g] = { curG[g], tG[g], nullptr, nullptr, nullptr,
                        offP[g], pairsP[g], Ps[g], pb };
            pb += (Ps[g] + 3) / 4;
            TN.g[g] = { tG[g], curG[g], obG[g], (float*)d_out + out_off[g],
                        (const float*)d_in[g], offN[g], pairsN[g], Ns[g], nb };
            nb += (Ns[g] + 3) / 4;
        }
        if (useOB) {
            spmm_kernel<0><<<pb, 256, 0, stream>>>(TP);
            spmm_kernel<1><<<nb, 256, 0, stream>>>(TN);
            spmm_kernel<0><<<pb, 256, 0, stream>>>(TP);
            spmm_kernel<2><<<nb, 256, 0, stream>>>(TN);
            spmm_kernel<0><<<pb, 256, 0, stream>>>(TP);
            spmm_kernel<3><<<nb, 256, 0, stream>>>(TN);
        } else {
            spmm_kernel<0><<<pb, 256, 0, stream>>>(TP);
            spmm_kernel<4><<<nb, 256, 0, stream>>>(TN);
            spmm_kernel<0><<<pb, 256, 0, stream>>>(TP);
            spmm_kernel<5><<<nb, 256, 0, stream>>>(TN);
            spmm_kernel<0><<<pb, 256, 0, stream>>>(TP);
            spmm_kernel<6><<<nb, 256, 0, stream>>>(TN);
        }
    } else {
        // shared-buffer fallback: per-graph sequential, 1-entry tables, fp32
        const int BIG = 0x7FFFFFFF;
        for (int g = 0; g < 4; ++g) {
            const float* emb = (const float*)d_in[g];
            float* outg = (float*)d_out + out_off[g];
            const int N = Ns[g], P = Ps[g];
            int n8 = N * D / 8;
            CvtG4 C;
            C.c[0] = { emb, (uint4*)curG[g], n8, 0 };
            for (int i = 1; i < 4; ++i) C.c[i].blkBase = BIG;
            cvt_bf16_kernel<<<(n8 + 255) / 256, 256, 0, stream>>>(C);

            SpmmG4 TP, TN;
            TP.g[0] = { curG[g], tG[g], nullptr, nullptr, nullptr,
                        offP[g], pairsP[g], P, 0 };
            TN.g[0] = { tG[g], curG[g], nullptr, outg, emb,
                        offN[g], pairsN[g], N, 0 };
            for (int i = 1; i < 4; ++i) { TP.g[i].blkBase = BIG; TN.g[i].blkBase = BIG; }
            int gp = (P + 3) / 4, gn = (N + 3) / 4;
            spmm_kernel<0><<<gp, 256, 0, stream>>>(TP);
            spmm_kernel<4><<<gn, 256, 0, stream>>>(TN);
            spmm_kernel<0><<<gp, 256, 0, stream>>>(TP);
            spmm_kernel<5><<<gn, 256, 0, stream>>>(TN);
            spmm_kernel<0><<<gp, 256, 0, stream>>>(TP);
            spmm_kernel<6><<<gn, 256, 0, stream>>>(TN);
        }
    }
}

// Round 8
// 1216.813 us; speedup vs baseline: 1.1204x; 1.0348x over previous
//
#include <hip/hip_runtime.h>

// ---------------------------------------------------------------------------
// LightGCN-style propagation, 4 independent bipartite graphs.
// R11: u32 packed pairs + packed-fp32 FMA.
// R10 post-mortem: byte cuts track 1:1 with time (spmm = cache-throughput
// bound). Top dispatch now P-side MODE0 (165us, FETCH 383MB, VALU 59%).
// Lever: src<2^17 and vals in [0,1) (bf16 top bit 0) -> edge packs into ONE
// u32: src | (bf16(val)>>1)<<17. Halves pair reads in all 6 spmm dispatches
// (-211MB), halves permute pair writes + LDS tile (2x occupancy). The +3
// VALU/edge unpack is offset by float2 ext-vector accumulate (v_pk_fma_f32:
// 16 -> 12 insts per 8 elems). Precision: one extra bf16 RNE on val (~0.4%),
// same magnitude as the passing bf16 row rounding.
// Build (R6-R8b): countB -> scanB -> partition (staged int2 (src|dl<<17,
// valf32)) -> permute (LDS counting sort -> CSR off[] + packed u32 pairs).
// bf16 accumulator chain (R10): MODE1/2 keep running sum in bf16, MODE3
// writes fp32. fp32 fallback modes 4/5/6 if ws is tight.
// ---------------------------------------------------------------------------

#define D 128
#define NC 64          // partition chunks per stream
#define TILE_CAP 7168  // permute LDS tile capacity (edges)
#define MAX_NB 512     // max dest-buckets per stream

// native clang vectors (accepted by __builtin_nontemporal_load / packed ops)
typedef int   vint4   __attribute__((ext_vector_type(4)));
typedef float vfloat4 __attribute__((ext_vector_type(4)));
typedef float vfloat2 __attribute__((ext_vector_type(2)));

// ---- bf16 helpers (RNE pack, bit-shift unpack) ----
__device__ __forceinline__ unsigned f2bf(float f) {
    unsigned u = __float_as_uint(f);
    u += 0x7FFFu + ((u >> 16) & 1u);
    return u >> 16;
}
__device__ __forceinline__ float bflo(unsigned u) { return __uint_as_float(u << 16); }
__device__ __forceinline__ float bfhi(unsigned u) { return __uint_as_float(u & 0xFFFF0000u); }

// ---- fp32 -> bf16 row conversion, fused over graphs ----
struct CvtG { const float* x; uint4* y; int n8, blkBase; };
struct CvtG4 { CvtG c[4]; };

__global__ __launch_bounds__(256) void cvt_bf16_kernel(CvtG4 Cd)
{
    int blk = blockIdx.x;
    int gi = (blk >= Cd.c[1].blkBase) + (blk >= Cd.c[2].blkBase)
           + (blk >= Cd.c[3].blkBase);
    const CvtG E = Cd.c[gi];
    int i = (blk - E.blkBase) * 256 + threadIdx.x;
    if (i >= E.n8) return;
    const float4* xp = (const float4*)E.x + (size_t)i * 2;
    float4 a = xp[0], b = xp[1];
    uint4 o;
    o.x = f2bf(a.x) | (f2bf(a.y) << 16);
    o.y = f2bf(a.z) | (f2bf(a.w) << 16);
    o.z = f2bf(b.x) | (f2bf(b.y) << 16);
    o.w = f2bf(b.z) | (f2bf(b.w) << 16);
    E.y[i] = o;
}

// ---- per-(graph,dir) stream descriptor ----
struct BStream {
    const int* dst; const int* src; const float* vals;
    int2* staged;        // K3 output (src|dl<<17, val f32), bucket-major
    unsigned* pairs;     // final CSR pairs, packed src|bf15val<<17
    int* off;            // final CSR offsets [n+1]
    int nnz, n, wshift, nb, cbase;
};
struct B8 {
    BStream s[8];
    int* cnt;            // [sum(nb+1)][NC]: counts -> cursor starts (K2 rewrite)
    int* gBB;            // [sum(nb+1)]: bucket bases + per-stream sentinel
    int pb[8];           // permute-block base per stream
};

// ---- K1: coarse bucket histogram, one dst pass (nt streaming reads) ----
__global__ __launch_bounds__(512) void countB_kernel(B8 G)
{
    const BStream S = G.s[blockIdx.y];
    int c = blockIdx.x;
    __shared__ int h[MAX_NB];
    for (int i = threadIdx.x; i < S.nb; i += 512) h[i] = 0;
    __syncthreads();
    int len = (((S.nnz + NC - 1) / NC) + 3) & ~3;
    int e0 = c * len, e1 = min(S.nnz, e0 + len);
    if (e0 < e1) {
        int nq = (e1 - e0) >> 2;
        const vint4* dq = (const vint4*)(S.dst + e0);
        for (int i = threadIdx.x; i < nq; i += 512) {
            vint4 v = __builtin_nontemporal_load(&dq[i]);
            atomicAdd(&h[v.x >> S.wshift], 1);
            atomicAdd(&h[v.y >> S.wshift], 1);
            atomicAdd(&h[v.z >> S.wshift], 1);
            atomicAdd(&h[v.w >> S.wshift], 1);
        }
        for (int e = e0 + (nq << 2) + (int)threadIdx.x; e < e1; e += 512)
            atomicAdd(&h[S.dst[e] >> S.wshift], 1);
    }
    __syncthreads();
    int* out = G.cnt + (size_t)S.cbase * NC;
    for (int i = threadIdx.x; i < S.nb; i += 512) out[(size_t)i * NC + c] = h[i];
}

// ---- K2: bucket totals + exscan -> bases and per-chunk cursor starts ----
__global__ __launch_bounds__(512) void scanB_kernel(B8 G)
{
    const BStream S = G.s[blockIdx.x];
    int* cnt = G.cnt + (size_t)S.cbase * NC;
    int* bb  = G.gBB + S.cbase;
    __shared__ int wsum[8];
    int b = threadIdx.x;
    int t = 0;
    if (b < S.nb) {
        int* row = cnt + (size_t)b * NC;
        int run = 0;
        #pragma unroll
        for (int c = 0; c < NC; ++c) { int v = row[c]; row[c] = run; run += v; }
        t = run;
    }
    int lane = b & 63, w = b >> 6;
    int x = t;
    #pragma unroll
    for (int s = 1; s < 64; s <<= 1) {
        int y = __shfl_up(x, s, 64);
        if (lane >= s) x += y;
    }
    if (lane == 63) wsum[w] = x;
    __syncthreads();
    if (b == 0) {
        int run = 0;
        #pragma unroll
        for (int i = 0; i < 8; ++i) { int v = wsum[i]; wsum[i] = run; run += v; }
    }
    __syncthreads();
    int excl = wsum[w] + x - t;
    if (b < S.nb) {
        bb[b] = excl;
        int* row = cnt + (size_t)b * NC;
        #pragma unroll
        for (int c = 0; c < NC; ++c) row[c] += excl;
    }
    if (b == 0) { bb[S.nb] = S.nnz; S.off[S.n] = S.nnz; }
}

// ---- K3: partition edges bucket-major, staged (src|dl<<17, val f32) ----
__global__ __launch_bounds__(512) void partition_kernel(B8 G)
{
    const BStream S = G.s[blockIdx.y];
    int c = blockIdx.x;
    __shared__ int cur[MAX_NB];
    const int* cs = G.cnt + (size_t)S.cbase * NC;
    for (int i = threadIdx.x; i < S.nb; i += 512) cur[i] = cs[(size_t)i * NC + c];
    __syncthreads();
    int len = (((S.nnz + NC - 1) / NC) + 3) & ~3;
    int e0 = c * len, e1 = min(S.nnz, e0 + len);
    if (e0 >= e1) return;
    int smask = (1 << S.wshift) - 1;
    int nq = (e1 - e0) >> 2;
    const vint4*   dq = (const vint4*)(S.dst + e0);
    const vint4*   sq = (const vint4*)(S.src + e0);
    const vfloat4* vq = (const vfloat4*)(S.vals + e0);
    for (int i = threadIdx.x; i < nq; i += 512) {
        vint4 dv = __builtin_nontemporal_load(&dq[i]);
        vint4 sv = __builtin_nontemporal_load(&sq[i]);
        vfloat4 vv = __builtin_nontemporal_load(&vq[i]);
        int p;
        p = atomicAdd(&cur[dv.x >> S.wshift], 1);
        S.staged[p] = make_int2(sv.x | ((dv.x & smask) << 17), __float_as_int(vv.x));
        p = atomicAdd(&cur[dv.y >> S.wshift], 1);
        S.staged[p] = make_int2(sv.y | ((dv.y & smask) << 17), __float_as_int(vv.y));
        p = atomicAdd(&cur[dv.z >> S.wshift], 1);
        S.staged[p] = make_int2(sv.z | ((dv.z & smask) << 17), __float_as_int(vv.z));
        p = atomicAdd(&cur[dv.w >> S.wshift], 1);
        S.staged[p] = make_int2(sv.w | ((dv.w & smask) << 17), __float_as_int(vv.w));
    }
    for (int e = e0 + (nq << 2) + (int)threadIdx.x; e < e1; e += 512) {
        int d = S.dst[e];
        int p = atomicAdd(&cur[d >> S.wshift], 1);
        S.staged[p] = make_int2(S.src[e] | ((d & smask) << 17), __float_as_int(S.vals[e]));
    }
}

// ---- K4: per-bucket dest-sort through LDS; writes CSR off[] + u32 pairs ----
__global__ __launch_bounds__(512) void permute_kernel(B8 G)
{
    int gb = blockIdx.x;
    int s = 0;
    #pragma unroll
    for (int i = 1; i < 8; ++i) s += (gb >= G.pb[i]);
    const BStream S = G.s[s];
    int b = gb - G.pb[s];
    const int* bb = G.gBB + S.cbase;
    int B0 = bb[b], B1 = bb[b + 1];
    int cnt = B1 - B0;
    int span = 1 << S.wshift;
    int dbase = b << S.wshift;

    __shared__ unsigned tile[TILE_CAP];
    __shared__ int cursor[MAX_NB];
    __shared__ int wsum[8];
    int tid = threadIdx.x;

    for (int i = tid; i < span; i += 512) cursor[i] = 0;
    __syncthreads();
    for (int i = B0 + tid; i < B1; i += 512)
        atomicAdd(&cursor[((unsigned)S.staged[i].x) >> 17], 1);
    __syncthreads();

    // exclusive scan over span (<=512) counts
    int v = (tid < span) ? cursor[tid] : 0;
    int lane = tid & 63, w = tid >> 6;
    int x = v;
    #pragma unroll
    for (int st = 1; st < 64; st <<= 1) {
        int y = __shfl_up(x, st, 64);
        if (lane >= st) x += y;
    }
    if (lane == 63) wsum[w] = x;
    __syncthreads();
    if (tid == 0) {
        int run = 0;
        #pragma unroll
        for (int i = 0; i < 8; ++i) { int t = wsum[i]; wsum[i] = run; run += t; }
    }
    __syncthreads();
    int excl = wsum[w] + x - v;
    __syncthreads();
    if (tid < span) {
        int d = dbase + tid;
        if (d < S.n) S.off[d] = B0 + excl;
        cursor[tid] = excl;
    }
    __syncthreads();

    if (cnt <= TILE_CAP) {
        for (int i = B0 + tid; i < B1; i += 512) {
            int2 pe = S.staged[i];
            int dl = ((unsigned)pe.x) >> 17;
            int p = atomicAdd(&cursor[dl], 1);
            unsigned bf15 = f2bf(__int_as_float(pe.y)) & 0x7FFFu;
            tile[p] = ((unsigned)pe.x & 0x1FFFFu) | (bf15 << 17);
        }
        __syncthreads();
        for (int i = tid; i < cnt; i += 512) S.pairs[B0 + i] = tile[i];
    } else {
        // statistically-never fallback; staged != pairs so no in-place hazard
        for (int i = B0 + tid; i < B1; i += 512) {
            int2 pe = S.staged[i];
            int dl = ((unsigned)pe.x) >> 17;
            int p = atomicAdd(&cursor[dl], 1);
            unsigned bf15 = f2bf(__int_as_float(pe.y)) & 0x7FFFu;
            S.pairs[B0 + p] = ((unsigned)pe.x & 0x1FFFFu) | (bf15 << 17);
        }
    }
}

// ---- gather SpMM, fused over graphs via desc table ----
// bf16-accumulator modes (ob = bf16 running sum buffer):
//   MODE 0: y = acc                         (P-side -> t)
//   MODE 1: y = acc; ob = y_old(embbf)+acc  (N l1; y held emb_bf)
//   MODE 2: y = acc; ob += acc              (N l2)
//   MODE 3: out = (ob + acc) * 0.25         (N l3, fp32 final)
// fp32 fallback modes:
//   MODE 4: y = acc; out = aux + acc
//   MODE 5: y = acc; out += acc
//   MODE 6: out = (out + acc) * 0.25
struct SpmmG {
    const unsigned short* x;   // bf16 [n_src][128]
    unsigned short* y;         // bf16 [n_dst][128]
    unsigned short* ob;        // bf16 running sum [n_dst][128]
    float* out;                // fp32 [n_dst][128]
    const float* aux;          // fp32 emb (MODE 4)
    const int* off; const unsigned* pairs;
    int n_dst, blkBase;
};
struct SpmmG4 { SpmmG g[4]; };

__device__ __forceinline__ float pval(unsigned p) {
    return __uint_as_float((p >> 1) & 0xFFFF0000u);
}
__device__ __forceinline__ void fma8(vfloat2 a[4], uint4 g, float v) {
    vfloat2 vv; vv.x = v; vv.y = v;
    vfloat2 u;
    u.x = bflo(g.x); u.y = bfhi(g.x); a[0] = u * vv + a[0];
    u.x = bflo(g.y); u.y = bfhi(g.y); a[1] = u * vv + a[1];
    u.x = bflo(g.z); u.y = bfhi(g.z); a[2] = u * vv + a[2];
    u.x = bflo(g.w); u.y = bfhi(g.w); a[3] = u * vv + a[3];
}

template<int MODE>
__global__ __launch_bounds__(256) void spmm_kernel(SpmmG4 Gd)
{
    int blk = blockIdx.x;
    int gi = (blk >= Gd.g[1].blkBase) + (blk >= Gd.g[2].blkBase)
           + (blk >= Gd.g[3].blkBase);
    const SpmmG E = Gd.g[gi];
    int row = (blk - E.blkBase) * 4 + (threadIdx.x >> 6);
    if (row >= E.n_dst) return;
    int lane = threadIdx.x & 63;
    int q   = lane >> 4;     // quarter 0..3 -> edge j+q
    int l16 = lane & 15;     // elems l16*8 .. l16*8+7

    int s = E.off[row], e = E.off[row + 1];
    vfloat2 acc2[4];
    #pragma unroll
    for (int k = 0; k < 4; ++k) { acc2[k].x = 0.f; acc2[k].y = 0.f; }

    int j = s;
    for (; j + 7 < e; j += 8) {            // 8 edges/iter, all valid
        unsigned p0 = E.pairs[j + q];
        unsigned p1 = E.pairs[j + 4 + q];
        uint4 g0 = ((const uint4*)(E.x + ((long)(p0 & 0x1FFFFu) << 7)))[l16];
        uint4 g1 = ((const uint4*)(E.x + ((long)(p1 & 0x1FFFFu) << 7)))[l16];
        fma8(acc2, g0, pval(p0));
        fma8(acc2, g1, pval(p1));
    }
    for (; j < e; j += 4) {                // predicated tail quad
        if (j + q < e) {
            unsigned p = E.pairs[j + q];
            uint4 g = ((const uint4*)(E.x + ((long)(p & 0x1FFFFu) << 7)))[l16];
            fma8(acc2, g, pval(p));
        }
    }

    float acc[8] = { acc2[0].x, acc2[0].y, acc2[1].x, acc2[1].y,
                     acc2[2].x, acc2[2].y, acc2[3].x, acc2[3].y };
    #pragma unroll
    for (int k = 0; k < 8; ++k) {          // combine 4 quarter partials
        acc[k] += __shfl_xor(acc[k], 16);
        acc[k] += __shfl_xor(acc[k], 32);
    }
    if (q != 0) return;
    long rb = (long)row << 7;

    uint4 prev;                            // bf16 row read before y overwrite
    if (MODE == 1) prev = ((const uint4*)(E.y + rb))[l16];
    if (MODE == 2 || MODE == 3) prev = ((const uint4*)(E.ob + rb))[l16];

    if (MODE != 3 && MODE != 6) {
        uint4 o;
        o.x = f2bf(acc[0]) | (f2bf(acc[1]) << 16);
        o.y = f2bf(acc[2]) | (f2bf(acc[3]) << 16);
        o.z = f2bf(acc[4]) | (f2bf(acc[5]) << 16);
        o.w = f2bf(acc[6]) | (f2bf(acc[7]) << 16);
        ((uint4*)(E.y + rb))[l16] = o;
    }
    if (MODE == 1 || MODE == 2) {
        float b0 = acc[0] + bflo(prev.x), b1 = acc[1] + bfhi(prev.x);
        float b2 = acc[2] + bflo(prev.y), b3 = acc[3] + bfhi(prev.y);
        float b4 = acc[4] + bflo(prev.z), b5 = acc[5] + bfhi(prev.z);
        float b6 = acc[6] + bflo(prev.w), b7 = acc[7] + bfhi(prev.w);
        uint4 o;
        o.x = f2bf(b0) | (f2bf(b1) << 16);
        o.y = f2bf(b2) | (f2bf(b3) << 16);
        o.z = f2bf(b4) | (f2bf(b5) << 16);
        o.w = f2bf(b6) | (f2bf(b7) << 16);
        ((uint4*)(E.ob + rb))[l16] = o;
    } else if (MODE == 3) {
        float4* op = (float4*)(E.out + rb) + l16 * 2;
        float4 a0, a1;
        a0.x = (acc[0] + bflo(prev.x)) * 0.25f; a0.y = (acc[1] + bfhi(prev.x)) * 0.25f;
        a0.z = (acc[2] + bflo(prev.y)) * 0.25f; a0.w = (acc[3] + bfhi(prev.y)) * 0.25f;
        a1.x = (acc[4] + bflo(prev.z)) * 0.25f; a1.y = (acc[5] + bfhi(prev.z)) * 0.25f;
        a1.z = (acc[6] + bflo(prev.w)) * 0.25f; a1.w = (acc[7] + bfhi(prev.w)) * 0.25f;
        op[0] = a0; op[1] = a1;
    } else if (MODE == 4) {
        const float4* ap = (const float4*)(E.aux + rb) + l16 * 2;
        float4* op = (float4*)(E.out + rb) + l16 * 2;
        float4 a0 = ap[0], a1 = ap[1];
        a0.x += acc[0]; a0.y += acc[1]; a0.z += acc[2]; a0.w += acc[3];
        a1.x += acc[4]; a1.y += acc[5]; a1.z += acc[6]; a1.w += acc[7];
        op[0] = a0; op[1] = a1;
    } else if (MODE == 5) {
        float4* op = (float4*)(E.out + rb) + l16 * 2;
        float4 a0 = op[0], a1 = op[1];
        a0.x += acc[0]; a0.y += acc[1]; a0.z += acc[2]; a0.w += acc[3];
        a1.x += acc[4]; a1.y += acc[5]; a1.z += acc[6]; a1.w += acc[7];
        op[0] = a0; op[1] = a1;
    } else if (MODE == 6) {
        float4* op = (float4*)(E.out + rb) + l16 * 2;
        float4 a0 = op[0], a1 = op[1];
        a0.x = (a0.x + acc[0]) * 0.25f; a0.y = (a0.y + acc[1]) * 0.25f;
        a0.z = (a0.z + acc[2]) * 0.25f; a0.w = (a0.w + acc[3]) * 0.25f;
        a1.x = (a1.x + acc[4]) * 0.25f; a1.y = (a1.y + acc[5]) * 0.25f;
        a1.z = (a1.z + acc[6]) * 0.25f; a1.w = (a1.w + acc[7]) * 0.25f;
        op[0] = a0; op[1] = a1;
    }
}

extern "C" void kernel_launch(void* const* d_in, const int* in_sizes, int n_in,
                              void* d_out, int out_size, void* d_ws, size_t ws_size,
                              hipStream_t stream)
{
    static const int Ns[4] = {100000, 40000, 20000, 10000};
    static const int Ps[4] = { 40000, 100000, 100000, 40000};
    const int maxN = 100000, maxP = 100000;

    int nnz[4];
    for (int g = 0; g < 4; ++g) nnz[g] = in_sizes[4 + g];

    // wshift: largest span (pow2, <=512) with expected edges <= 5120/bucket
    auto calc_ws = [](int n, int m) {
        int ws = 0;
        while (ws < 9 && (double)m * (double)(1 << (ws + 1)) <= 5120.0 * n) ++ws;
        while (((n + (1 << ws) - 1) >> ws) > MAX_NB) ++ws;
        return ws;
    };

    // ---- stream geometry (pointer-free) ----
    B8 G;
    int cbase = 0, pbTot = 0;
    for (int g = 0; g < 4; ++g)
        for (int dir = 0; dir < 2; ++dir) {
            BStream& s = G.s[2 * g + dir];
            s.nnz = nnz[g];
            s.n   = dir ? Ns[g] : Ps[g];
            s.wshift = calc_ws(s.n, s.nnz);
            s.nb = (s.n + (1 << s.wshift) - 1) >> s.wshift;
            s.cbase = cbase;
            G.pb[2 * g + dir] = pbTot;
            cbase += s.nb + 1;
            pbTot += s.nb;
        }

    // ---- ws budgets: perGraph cur/t; +ob (bf16 running sum) ----
    auto padded = [](size_t b) { return (b + 255) & ~(size_t)255; };
    size_t need = 0;
    for (int g = 0; g < 4; ++g) need += padded((size_t)Ns[g] * D * 2)
                                      + padded((size_t)Ps[g] * D * 2);
    for (int g = 0; g < 4; ++g) need += padded((size_t)(Ps[g] + 1) * 4)
                                      + padded((size_t)(Ns[g] + 1) * 4);
    for (int g = 0; g < 4; ++g) need += 2 * padded((size_t)nnz[g] * 4);
    need += padded((size_t)cbase * NC * 4) + padded((size_t)cbase * 4);
    size_t needOB = need;
    for (int g = 0; g < 4; ++g) needOB += padded((size_t)Ns[g] * D * 2);
    bool perGraph = need <= ws_size;
    bool useOB = needOB <= ws_size;

    // ---- workspace carve ----
    char* wp = (char*)d_ws;
    auto alloc = [&](size_t bytes) -> void* {
        void* p = (void*)wp; wp += (bytes + 255) & ~(size_t)255; return p;
    };
    unsigned short* curG[4]; unsigned short* tG[4]; unsigned short* obG[4];
    if (perGraph) {
        for (int g = 0; g < 4; ++g) {
            curG[g] = (unsigned short*)alloc((size_t)Ns[g] * D * 2);
            tG[g]   = (unsigned short*)alloc((size_t)Ps[g] * D * 2);
        }
    } else {
        unsigned short* cur = (unsigned short*)alloc((size_t)maxN * D * 2);
        unsigned short* t   = (unsigned short*)alloc((size_t)maxP * D * 2);
        for (int g = 0; g < 4; ++g) { curG[g] = cur; tG[g] = t; }
    }
    int* offP[4]; int* offN[4]; unsigned* pairsP[4]; unsigned* pairsN[4];
    for (int g = 0; g < 4; ++g) {
        offP[g] = (int*)alloc((size_t)(Ps[g] + 1) * sizeof(int));
        offN[g] = (int*)alloc((size_t)(Ns[g] + 1) * sizeof(int));
    }
    for (int g = 0; g < 4; ++g) {
        pairsP[g] = (unsigned*)alloc((size_t)nnz[g] * sizeof(unsigned));
        pairsN[g] = (unsigned*)alloc((size_t)nnz[g] * sizeof(unsigned));
    }
    G.cnt = (int*)alloc((size_t)cbase * NC * sizeof(int));
    G.gBB = (int*)alloc((size_t)cbase * sizeof(int));
    if (useOB)
        for (int g = 0; g < 4; ++g)
            obG[g] = (unsigned short*)alloc((size_t)Ns[g] * D * 2);
    else
        for (int g = 0; g < 4; ++g) obG[g] = nullptr;

    // staged packed int2 -> d_out (fully consumed by permute before spmm)
    int2* stagedBase = (int2*)d_out;
    size_t soff = 0;
    for (int g = 0; g < 4; ++g)
        for (int dir = 0; dir < 2; ++dir) {
            BStream& s = G.s[2 * g + dir];
            s.dst  = (const int*)d_in[8 + 2 * g + (dir ? 1 : 0)];
            s.src  = (const int*)d_in[8 + 2 * g + (dir ? 0 : 1)];
            s.vals = (const float*)d_in[4 + g];
            s.off  = dir ? offN[g] : offP[g];
            s.pairs = dir ? pairsN[g] : pairsP[g];
            s.staged = stagedBase + soff;
            soff += (size_t)nnz[g];
        }

    // ---- CSR build: count -> scan -> partition -> permute ----
    countB_kernel<<<dim3(NC, 8), 512, 0, stream>>>(G);
    scanB_kernel<<<8, 512, 0, stream>>>(G);
    partition_kernel<<<dim3(NC, 8), 512, 0, stream>>>(G);
    permute_kernel<<<pbTot, 512, 0, stream>>>(G);

    // ---- propagation ----
    size_t out_off[4]; size_t oo = 0;
    for (int g = 0; g < 4; ++g) { out_off[g] = oo; oo += (size_t)Ns[g] * D; }

    if (perGraph) {
        // one cvt dispatch, then 2 fused spmm dispatches per layer
        CvtG4 C; int cb = 0;
        for (int g = 0; g < 4; ++g) {
            int n8 = Ns[g] * D / 8;
            C.c[g] = { (const float*)d_in[g], (uint4*)curG[g], n8, cb };
            cb += (n8 + 255) / 256;
        }
        cvt_bf16_kernel<<<cb, 256, 0, stream>>>(C);

        SpmmG4 TP, TN;
        int pb = 0, nb = 0;
        for (int g = 0; g < 4; ++g) {
            TP.g[g] = { curG[g], tG[g], nullptr, nullptr, nullptr,
                        offP[g], pairsP[g], Ps[g], pb };
            pb += (Ps[g] + 3) / 4;
            TN.g[g] = { tG[g], curG[g], obG[g], (float*)d_out + out_off[g],
                        (const float*)d_in[g], offN[g], pairsN[g], Ns[g], nb };
            nb += (Ns[g] + 3) / 4;
        }
        if (useOB) {
            spmm_kernel<0><<<pb, 256, 0, stream>>>(TP);
            spmm_kernel<1><<<nb, 256, 0, stream>>>(TN);
            spmm_kernel<0><<<pb, 256, 0, stream>>>(TP);
            spmm_kernel<2><<<nb, 256, 0, stream>>>(TN);
            spmm_kernel<0><<<pb, 256, 0, stream>>>(TP);
            spmm_kernel<3><<<nb, 256, 0, stream>>>(TN);
        } else {
            spmm_kernel<0><<<pb, 256, 0, stream>>>(TP);
            spmm_kernel<4><<<nb, 256, 0, stream>>>(TN);
            spmm_kernel<0><<<pb, 256, 0, stream>>>(TP);
            spmm_kernel<5><<<nb, 256, 0, stream>>>(TN);
            spmm_kernel<0><<<pb, 256, 0, stream>>>(TP);
            spmm_kernel<6><<<nb, 256, 0, stream>>>(TN);
        }
    } else {
        // shared-buffer fallback: per-graph sequential, 1-entry tables, fp32
        const int BIG = 0x7FFFFFFF;
        for (int g = 0; g < 4; ++g) {
            const float* emb = (const float*)d_in[g];
            float* outg = (float*)d_out + out_off[g];
            const int N = Ns[g], P = Ps[g];
            int n8 = N * D / 8;
            CvtG4 C;
            C.c[0] = { emb, (uint4*)curG[g], n8, 0 };
            for (int i = 1; i < 4; ++i) C.c[i].blkBase = BIG;
            cvt_bf16_kernel<<<(n8 + 255) / 256, 256, 0, stream>>>(C);

            SpmmG4 TP, TN;
            TP.g[0] = { curG[g], tG[g], nullptr, nullptr, nullptr,
                        offP[g], pairsP[g], P, 0 };
            TN.g[0] = { tG[g], curG[g], nullptr, outg, emb,
                        offN[g], pairsN[g], N, 0 };
            for (int i = 1; i < 4; ++i) { TP.g[i].blkBase = BIG; TN.g[i].blkBase = BIG; }
            int gp = (P + 3) / 4, gn = (N + 3) / 4;
            spmm_kernel<0><<<gp, 256, 0, stream>>>(TP);
            spmm_kernel<4><<<gn, 256, 0, stream>>>(TN);
            spmm_kernel<0><<<gp, 256, 0, stream>>>(TP);
            spmm_kernel<5><<<gn, 256, 0, stream>>>(TN);
            spmm_kernel<0><<<gp, 256, 0, stream>>>(TP);
            spmm_kernel<6><<<gn, 256, 0, stream>>>(TN);
        }
    }
}

// Round 9
// 1174.101 us; speedup vs baseline: 1.1612x; 1.0364x over previous
//
#include <hip/hip_runtime.h>

// ---------------------------------------------------------------------------
// LightGCN-style propagation, 4 independent bipartite graphs.
// R12: (a) drop the bf16 running-sum buffer: layer N-outputs live in their
// own buffers (e_bf, c1, c2); N L1/L2 are plain MODE0 writes; final MODE3
// reads e_bf+c1+c2 once -> -87MB fabric traffic vs the R10/R11 ob chain
// (old: MODE1 r43.5+w43.5, MODE2 rw87, MODE3 r43.5 = 217MB; new: 130.5MB).
// (b) 16-edge unroll level in the gather loop (2->4 outstanding gathers per
// lane; no register rotation, no nt loads - the parts of R9 that backfired).
// R11 post-mortem: N-side FETCH 464MB is BELOW the 8-private-L2 random
// gather floor (8 x 71.7MB) -> no locality left at bf16 width; only byte
// cuts and MLP remain.
// Build (R6-R11): countB -> scanB -> partition (staged int2 (src|dl<<17,
// valf32), nt reads, 512thr) -> permute (LDS counting sort -> CSR off[] +
// u32-packed pairs src|bf15val<<17). All coalesced, no global atomics.
// ---------------------------------------------------------------------------

#define D 128
#define NC 64          // partition chunks per stream
#define TILE_CAP 7168  // permute LDS tile capacity (edges)
#define MAX_NB 512     // max dest-buckets per stream

// native clang vectors (accepted by __builtin_nontemporal_load / packed ops)
typedef int   vint4   __attribute__((ext_vector_type(4)));
typedef float vfloat4 __attribute__((ext_vector_type(4)));
typedef float vfloat2 __attribute__((ext_vector_type(2)));

// ---- bf16 helpers (RNE pack, bit-shift unpack) ----
__device__ __forceinline__ unsigned f2bf(float f) {
    unsigned u = __float_as_uint(f);
    u += 0x7FFFu + ((u >> 16) & 1u);
    return u >> 16;
}
__device__ __forceinline__ float bflo(unsigned u) { return __uint_as_float(u << 16); }
__device__ __forceinline__ float bfhi(unsigned u) { return __uint_as_float(u & 0xFFFF0000u); }

// ---- fp32 -> bf16 row conversion, fused over graphs ----
struct CvtG { const float* x; uint4* y; int n8, blkBase; };
struct CvtG4 { CvtG c[4]; };

__global__ __launch_bounds__(256) void cvt_bf16_kernel(CvtG4 Cd)
{
    int blk = blockIdx.x;
    int gi = (blk >= Cd.c[1].blkBase) + (blk >= Cd.c[2].blkBase)
           + (blk >= Cd.c[3].blkBase);
    const CvtG E = Cd.c[gi];
    int i = (blk - E.blkBase) * 256 + threadIdx.x;
    if (i >= E.n8) return;
    const float4* xp = (const float4*)E.x + (size_t)i * 2;
    float4 a = xp[0], b = xp[1];
    uint4 o;
    o.x = f2bf(a.x) | (f2bf(a.y) << 16);
    o.y = f2bf(a.z) | (f2bf(a.w) << 16);
    o.z = f2bf(b.x) | (f2bf(b.y) << 16);
    o.w = f2bf(b.z) | (f2bf(b.w) << 16);
    E.y[i] = o;
}

// ---- per-(graph,dir) stream descriptor ----
struct BStream {
    const int* dst; const int* src; const float* vals;
    int2* staged;        // K3 output (src|dl<<17, val f32), bucket-major
    unsigned* pairs;     // final CSR pairs, packed src|bf15val<<17
    int* off;            // final CSR offsets [n+1]
    int nnz, n, wshift, nb, cbase;
};
struct B8 {
    BStream s[8];
    int* cnt;            // [sum(nb+1)][NC]: counts -> cursor starts (K2 rewrite)
    int* gBB;            // [sum(nb+1)]: bucket bases + per-stream sentinel
    int pb[8];           // permute-block base per stream
};

// ---- K1: coarse bucket histogram, one dst pass (nt streaming reads) ----
__global__ __launch_bounds__(512) void countB_kernel(B8 G)
{
    const BStream S = G.s[blockIdx.y];
    int c = blockIdx.x;
    __shared__ int h[MAX_NB];
    for (int i = threadIdx.x; i < S.nb; i += 512) h[i] = 0;
    __syncthreads();
    int len = (((S.nnz + NC - 1) / NC) + 3) & ~3;
    int e0 = c * len, e1 = min(S.nnz, e0 + len);
    if (e0 < e1) {
        int nq = (e1 - e0) >> 2;
        const vint4* dq = (const vint4*)(S.dst + e0);
        for (int i = threadIdx.x; i < nq; i += 512) {
            vint4 v = __builtin_nontemporal_load(&dq[i]);
            atomicAdd(&h[v.x >> S.wshift], 1);
            atomicAdd(&h[v.y >> S.wshift], 1);
            atomicAdd(&h[v.z >> S.wshift], 1);
            atomicAdd(&h[v.w >> S.wshift], 1);
        }
        for (int e = e0 + (nq << 2) + (int)threadIdx.x; e < e1; e += 512)
            atomicAdd(&h[S.dst[e] >> S.wshift], 1);
    }
    __syncthreads();
    int* out = G.cnt + (size_t)S.cbase * NC;
    for (int i = threadIdx.x; i < S.nb; i += 512) out[(size_t)i * NC + c] = h[i];
}

// ---- K2: bucket totals + exscan -> bases and per-chunk cursor starts ----
__global__ __launch_bounds__(512) void scanB_kernel(B8 G)
{
    const BStream S = G.s[blockIdx.x];
    int* cnt = G.cnt + (size_t)S.cbase * NC;
    int* bb  = G.gBB + S.cbase;
    __shared__ int wsum[8];
    int b = threadIdx.x;
    int t = 0;
    if (b < S.nb) {
        int* row = cnt + (size_t)b * NC;
        int run = 0;
        #pragma unroll
        for (int c = 0; c < NC; ++c) { int v = row[c]; row[c] = run; run += v; }
        t = run;
    }
    int lane = b & 63, w = b >> 6;
    int x = t;
    #pragma unroll
    for (int s = 1; s < 64; s <<= 1) {
        int y = __shfl_up(x, s, 64);
        if (lane >= s) x += y;
    }
    if (lane == 63) wsum[w] = x;
    __syncthreads();
    if (b == 0) {
        int run = 0;
        #pragma unroll
        for (int i = 0; i < 8; ++i) { int v = wsum[i]; wsum[i] = run; run += v; }
    }
    __syncthreads();
    int excl = wsum[w] + x - t;
    if (b < S.nb) {
        bb[b] = excl;
        int* row = cnt + (size_t)b * NC;
        #pragma unroll
        for (int c = 0; c < NC; ++c) row[c] += excl;
    }
    if (b == 0) { bb[S.nb] = S.nnz; S.off[S.n] = S.nnz; }
}

// ---- K3: partition edges bucket-major, staged (src|dl<<17, val f32) ----
__global__ __launch_bounds__(512) void partition_kernel(B8 G)
{
    const BStream S = G.s[blockIdx.y];
    int c = blockIdx.x;
    __shared__ int cur[MAX_NB];
    const int* cs = G.cnt + (size_t)S.cbase * NC;
    for (int i = threadIdx.x; i < S.nb; i += 512) cur[i] = cs[(size_t)i * NC + c];
    __syncthreads();
    int len = (((S.nnz + NC - 1) / NC) + 3) & ~3;
    int e0 = c * len, e1 = min(S.nnz, e0 + len);
    if (e0 >= e1) return;
    int smask = (1 << S.wshift) - 1;
    int nq = (e1 - e0) >> 2;
    const vint4*   dq = (const vint4*)(S.dst + e0);
    const vint4*   sq = (const vint4*)(S.src + e0);
    const vfloat4* vq = (const vfloat4*)(S.vals + e0);
    for (int i = threadIdx.x; i < nq; i += 512) {
        vint4 dv = __builtin_nontemporal_load(&dq[i]);
        vint4 sv = __builtin_nontemporal_load(&sq[i]);
        vfloat4 vv = __builtin_nontemporal_load(&vq[i]);
        int p;
        p = atomicAdd(&cur[dv.x >> S.wshift], 1);
        S.staged[p] = make_int2(sv.x | ((dv.x & smask) << 17), __float_as_int(vv.x));
        p = atomicAdd(&cur[dv.y >> S.wshift], 1);
        S.staged[p] = make_int2(sv.y | ((dv.y & smask) << 17), __float_as_int(vv.y));
        p = atomicAdd(&cur[dv.z >> S.wshift], 1);
        S.staged[p] = make_int2(sv.z | ((dv.z & smask) << 17), __float_as_int(vv.z));
        p = atomicAdd(&cur[dv.w >> S.wshift], 1);
        S.staged[p] = make_int2(sv.w | ((dv.w & smask) << 17), __float_as_int(vv.w));
    }
    for (int e = e0 + (nq << 2) + (int)threadIdx.x; e < e1; e += 512) {
        int d = S.dst[e];
        int p = atomicAdd(&cur[d >> S.wshift], 1);
        S.staged[p] = make_int2(S.src[e] | ((d & smask) << 17), __float_as_int(S.vals[e]));
    }
}

// ---- K4: per-bucket dest-sort through LDS; writes CSR off[] + u32 pairs ----
__global__ __launch_bounds__(512) void permute_kernel(B8 G)
{
    int gb = blockIdx.x;
    int s = 0;
    #pragma unroll
    for (int i = 1; i < 8; ++i) s += (gb >= G.pb[i]);
    const BStream S = G.s[s];
    int b = gb - G.pb[s];
    const int* bb = G.gBB + S.cbase;
    int B0 = bb[b], B1 = bb[b + 1];
    int cnt = B1 - B0;
    int span = 1 << S.wshift;
    int dbase = b << S.wshift;

    __shared__ unsigned tile[TILE_CAP];
    __shared__ int cursor[MAX_NB];
    __shared__ int wsum[8];
    int tid = threadIdx.x;

    for (int i = tid; i < span; i += 512) cursor[i] = 0;
    __syncthreads();
    for (int i = B0 + tid; i < B1; i += 512)
        atomicAdd(&cursor[((unsigned)S.staged[i].x) >> 17], 1);
    __syncthreads();

    // exclusive scan over span (<=512) counts
    int v = (tid < span) ? cursor[tid] : 0;
    int lane = tid & 63, w = tid >> 6;
    int x = v;
    #pragma unroll
    for (int st = 1; st < 64; st <<= 1) {
        int y = __shfl_up(x, st, 64);
        if (lane >= st) x += y;
    }
    if (lane == 63) wsum[w] = x;
    __syncthreads();
    if (tid == 0) {
        int run = 0;
        #pragma unroll
        for (int i = 0; i < 8; ++i) { int t = wsum[i]; wsum[i] = run; run += t; }
    }
    __syncthreads();
    int excl = wsum[w] + x - v;
    __syncthreads();
    if (tid < span) {
        int d = dbase + tid;
        if (d < S.n) S.off[d] = B0 + excl;
        cursor[tid] = excl;
    }
    __syncthreads();

    if (cnt <= TILE_CAP) {
        for (int i = B0 + tid; i < B1; i += 512) {
            int2 pe = S.staged[i];
            int dl = ((unsigned)pe.x) >> 17;
            int p = atomicAdd(&cursor[dl], 1);
            unsigned bf15 = f2bf(__int_as_float(pe.y)) & 0x7FFFu;
            tile[p] = ((unsigned)pe.x & 0x1FFFFu) | (bf15 << 17);
        }
        __syncthreads();
        for (int i = tid; i < cnt; i += 512) S.pairs[B0 + i] = tile[i];
    } else {
        // statistically-never fallback; staged != pairs so no in-place hazard
        for (int i = B0 + tid; i < B1; i += 512) {
            int2 pe = S.staged[i];
            int dl = ((unsigned)pe.x) >> 17;
            int p = atomicAdd(&cursor[dl], 1);
            unsigned bf15 = f2bf(__int_as_float(pe.y)) & 0x7FFFu;
            S.pairs[B0 + p] = ((unsigned)pe.x & 0x1FFFFu) | (bf15 << 17);
        }
    }
}

// ---- gather SpMM, fused over graphs via desc table ----
//   MODE 0: y = acc                               (all P-sides, N L1/L2)
//   MODE 3: out = (ebf + c1 + c2 + acc) * 0.25    (N L3, fp32 final)
// fp32 fallback modes (shared-buffer path):
//   MODE 4: y = acc; out = aux + acc
//   MODE 5: y = acc; out += acc
//   MODE 6: out = (out + acc) * 0.25
struct SpmmG {
    const unsigned short* x;   // bf16 gather source [n_src][128]
    unsigned short* y;         // MODE0/4/5 write target; MODE3: e_bf (read)
    const unsigned short* r1;  // MODE3: c1
    const unsigned short* r2;  // MODE3: c2
    float* out;                // fp32 [n_dst][128]
    const float* aux;          // fp32 emb (MODE 4)
    const int* off; const unsigned* pairs;
    int n_dst, blkBase;
};
struct SpmmG4 { SpmmG g[4]; };

__device__ __forceinline__ float pval(unsigned p) {
    return __uint_as_float((p >> 1) & 0xFFFF0000u);
}
__device__ __forceinline__ void fma8(vfloat2 a[4], uint4 g, float v) {
    vfloat2 vv; vv.x = v; vv.y = v;
    vfloat2 u;
    u.x = bflo(g.x); u.y = bfhi(g.x); a[0] = u * vv + a[0];
    u.x = bflo(g.y); u.y = bfhi(g.y); a[1] = u * vv + a[1];
    u.x = bflo(g.z); u.y = bfhi(g.z); a[2] = u * vv + a[2];
    u.x = bflo(g.w); u.y = bfhi(g.w); a[3] = u * vv + a[3];
}

template<int MODE>
__global__ __launch_bounds__(256) void spmm_kernel(SpmmG4 Gd)
{
    int blk = blockIdx.x;
    int gi = (blk >= Gd.g[1].blkBase) + (blk >= Gd.g[2].blkBase)
           + (blk >= Gd.g[3].blkBase);
    const SpmmG E = Gd.g[gi];
    int row = (blk - E.blkBase) * 4 + (threadIdx.x >> 6);
    if (row >= E.n_dst) return;
    int lane = threadIdx.x & 63;
    int q   = lane >> 4;     // quarter 0..3 -> edge j+q
    int l16 = lane & 15;     // elems l16*8 .. l16*8+7

    int s = E.off[row], e = E.off[row + 1];
    vfloat2 acc2[4];
    #pragma unroll
    for (int k = 0; k < 4; ++k) { acc2[k].x = 0.f; acc2[k].y = 0.f; }

    int j = s;
    for (; j + 15 < e; j += 16) {          // 16 edges/iter, 4 gathers in flight
        unsigned p0 = E.pairs[j + q];
        unsigned p1 = E.pairs[j + 4 + q];
        unsigned p2 = E.pairs[j + 8 + q];
        unsigned p3 = E.pairs[j + 12 + q];
        uint4 g0 = ((const uint4*)(E.x + ((long)(p0 & 0x1FFFFu) << 7)))[l16];
        uint4 g1 = ((const uint4*)(E.x + ((long)(p1 & 0x1FFFFu) << 7)))[l16];
        uint4 g2 = ((const uint4*)(E.x + ((long)(p2 & 0x1FFFFu) << 7)))[l16];
        uint4 g3 = ((const uint4*)(E.x + ((long)(p3 & 0x1FFFFu) << 7)))[l16];
        fma8(acc2, g0, pval(p0));
        fma8(acc2, g1, pval(p1));
        fma8(acc2, g2, pval(p2));
        fma8(acc2, g3, pval(p3));
    }
    for (; j + 7 < e; j += 8) {            // 8 edges/iter
        unsigned p0 = E.pairs[j + q];
        unsigned p1 = E.pairs[j + 4 + q];
        uint4 g0 = ((const uint4*)(E.x + ((long)(p0 & 0x1FFFFu) << 7)))[l16];
        uint4 g1 = ((const uint4*)(E.x + ((long)(p1 & 0x1FFFFu) << 7)))[l16];
        fma8(acc2, g0, pval(p0));
        fma8(acc2, g1, pval(p1));
    }
    for (; j < e; j += 4) {                // predicated tail quad
        if (j + q < e) {
            unsigned p = E.pairs[j + q];
            uint4 g = ((const uint4*)(E.x + ((long)(p & 0x1FFFFu) << 7)))[l16];
            fma8(acc2, g, pval(p));
        }
    }

    float acc[8] = { acc2[0].x, acc2[0].y, acc2[1].x, acc2[1].y,
                     acc2[2].x, acc2[2].y, acc2[3].x, acc2[3].y };
    #pragma unroll
    for (int k = 0; k < 8; ++k) {          // combine 4 quarter partials
        acc[k] += __shfl_xor(acc[k], 16);
        acc[k] += __shfl_xor(acc[k], 32);
    }
    if (q != 0) return;
    long rb = (long)row << 7;

    if (MODE == 0 || MODE == 4 || MODE == 5) {
        uint4 o;
        o.x = f2bf(acc[0]) | (f2bf(acc[1]) << 16);
        o.y = f2bf(acc[2]) | (f2bf(acc[3]) << 16);
        o.z = f2bf(acc[4]) | (f2bf(acc[5]) << 16);
        o.w = f2bf(acc[6]) | (f2bf(acc[7]) << 16);
        ((uint4*)(E.y + rb))[l16] = o;
    }
    if (MODE == 3) {
        uint4 pe = ((const uint4*)(E.y  + rb))[l16];   // e_bf
        uint4 pc = ((const uint4*)(E.r1 + rb))[l16];   // c1
        uint4 pd = ((const uint4*)(E.r2 + rb))[l16];   // c2
        float4* op = (float4*)(E.out + rb) + l16 * 2;
        float4 a0, a1;
        a0.x = (acc[0] + bflo(pe.x) + bflo(pc.x) + bflo(pd.x)) * 0.25f;
        a0.y = (acc[1] + bfhi(pe.x) + bfhi(pc.x) + bfhi(pd.x)) * 0.25f;
        a0.z = (acc[2] + bflo(pe.y) + bflo(pc.y) + bflo(pd.y)) * 0.25f;
        a0.w = (acc[3] + bfhi(pe.y) + bfhi(pc.y) + bfhi(pd.y)) * 0.25f;
        a1.x = (acc[4] + bflo(pe.z) + bflo(pc.z) + bflo(pd.z)) * 0.25f;
        a1.y = (acc[5] + bfhi(pe.z) + bfhi(pc.z) + bfhi(pd.z)) * 0.25f;
        a1.z = (acc[6] + bflo(pe.w) + bflo(pc.w) + bflo(pd.w)) * 0.25f;
        a1.w = (acc[7] + bfhi(pe.w) + bfhi(pc.w) + bfhi(pd.w)) * 0.25f;
        op[0] = a0; op[1] = a1;
    } else if (MODE == 4) {
        const float4* ap = (const float4*)(E.aux + rb) + l16 * 2;
        float4* op = (float4*)(E.out + rb) + l16 * 2;
        float4 a0 = ap[0], a1 = ap[1];
        a0.x += acc[0]; a0.y += acc[1]; a0.z += acc[2]; a0.w += acc[3];
        a1.x += acc[4]; a1.y += acc[5]; a1.z += acc[6]; a1.w += acc[7];
        op[0] = a0; op[1] = a1;
    } else if (MODE == 5) {
        float4* op = (float4*)(E.out + rb) + l16 * 2;
        float4 a0 = op[0], a1 = op[1];
        a0.x += acc[0]; a0.y += acc[1]; a0.z += acc[2]; a0.w += acc[3];
        a1.x += acc[4]; a1.y += acc[5]; a1.z += acc[6]; a1.w += acc[7];
        op[0] = a0; op[1] = a1;
    } else if (MODE == 6) {
        float4* op = (float4*)(E.out + rb) + l16 * 2;
        float4 a0 = op[0], a1 = op[1];
        a0.x = (a0.x + acc[0]) * 0.25f; a0.y = (a0.y + acc[1]) * 0.25f;
        a0.z = (a0.z + acc[2]) * 0.25f; a0.w = (a0.w + acc[3]) * 0.25f;
        a1.x = (a1.x + acc[4]) * 0.25f; a1.y = (a1.y + acc[5]) * 0.25f;
        a1.z = (a1.z + acc[6]) * 0.25f; a1.w = (a1.w + acc[7]) * 0.25f;
        op[0] = a0; op[1] = a1;
    }
}

extern "C" void kernel_launch(void* const* d_in, const int* in_sizes, int n_in,
                              void* d_out, int out_size, void* d_ws, size_t ws_size,
                              hipStream_t stream)
{
    static const int Ns[4] = {100000, 40000, 20000, 10000};
    static const int Ps[4] = { 40000, 100000, 100000, 40000};
    const int maxN = 100000, maxP = 100000;

    int nnz[4];
    for (int g = 0; g < 4; ++g) nnz[g] = in_sizes[4 + g];

    // wshift: largest span (pow2, <=512) with expected edges <= 5120/bucket
    auto calc_ws = [](int n, int m) {
        int ws = 0;
        while (ws < 9 && (double)m * (double)(1 << (ws + 1)) <= 5120.0 * n) ++ws;
        while (((n + (1 << ws) - 1) >> ws) > MAX_NB) ++ws;
        return ws;
    };

    // ---- stream geometry (pointer-free) ----
    B8 G;
    int cbase = 0, pbTot = 0;
    for (int g = 0; g < 4; ++g)
        for (int dir = 0; dir < 2; ++dir) {
            BStream& s = G.s[2 * g + dir];
            s.nnz = nnz[g];
            s.n   = dir ? Ns[g] : Ps[g];
            s.wshift = calc_ws(s.n, s.nnz);
            s.nb = (s.n + (1 << s.wshift) - 1) >> s.wshift;
            s.cbase = cbase;
            G.pb[2 * g + dir] = pbTot;
            cbase += s.nb + 1;
            pbTot += s.nb;
        }

    // ---- ws budget: tier A = per-graph {e_bf,c1,c2,t} ----
    auto padded = [](size_t b) { return (b + 255) & ~(size_t)255; };
    size_t common = 0;
    for (int g = 0; g < 4; ++g) common += padded((size_t)(Ps[g] + 1) * 4)
                                        + padded((size_t)(Ns[g] + 1) * 4);
    for (int g = 0; g < 4; ++g) common += 2 * padded((size_t)nnz[g] * 4);
    common += padded((size_t)cbase * NC * 4) + padded((size_t)cbase * 4);
    size_t needA = common;
    for (int g = 0; g < 4; ++g) needA += 3 * padded((size_t)Ns[g] * D * 2)
                                       + padded((size_t)Ps[g] * D * 2);
    bool tierA = needA <= ws_size;

    // ---- workspace carve ----
    char* wp = (char*)d_ws;
    auto alloc = [&](size_t bytes) -> void* {
        void* p = (void*)wp; wp += (bytes + 255) & ~(size_t)255; return p;
    };
    unsigned short *ebfG[4], *c1G[4], *c2G[4], *tG[4];
    if (tierA) {
        for (int g = 0; g < 4; ++g) {
            ebfG[g] = (unsigned short*)alloc((size_t)Ns[g] * D * 2);
            c1G[g]  = (unsigned short*)alloc((size_t)Ns[g] * D * 2);
            c2G[g]  = (unsigned short*)alloc((size_t)Ns[g] * D * 2);
            tG[g]   = (unsigned short*)alloc((size_t)Ps[g] * D * 2);
        }
    } else {
        unsigned short* cur = (unsigned short*)alloc((size_t)maxN * D * 2);
        unsigned short* t   = (unsigned short*)alloc((size_t)maxP * D * 2);
        for (int g = 0; g < 4; ++g) {
            ebfG[g] = c1G[g] = c2G[g] = cur; tG[g] = t;
        }
    }
    int* offP[4]; int* offN[4]; unsigned* pairsP[4]; unsigned* pairsN[4];
    for (int g = 0; g < 4; ++g) {
        offP[g] = (int*)alloc((size_t)(Ps[g] + 1) * sizeof(int));
        offN[g] = (int*)alloc((size_t)(Ns[g] + 1) * sizeof(int));
    }
    for (int g = 0; g < 4; ++g) {
        pairsP[g] = (unsigned*)alloc((size_t)nnz[g] * sizeof(unsigned));
        pairsN[g] = (unsigned*)alloc((size_t)nnz[g] * sizeof(unsigned));
    }
    G.cnt = (int*)alloc((size_t)cbase * NC * sizeof(int));
    G.gBB = (int*)alloc((size_t)cbase * sizeof(int));

    // staged packed int2 -> d_out (fully consumed by permute before spmm)
    int2* stagedBase = (int2*)d_out;
    size_t soff = 0;
    for (int g = 0; g < 4; ++g)
        for (int dir = 0; dir < 2; ++dir) {
            BStream& s = G.s[2 * g + dir];
            s.dst  = (const int*)d_in[8 + 2 * g + (dir ? 1 : 0)];
            s.src  = (const int*)d_in[8 + 2 * g + (dir ? 0 : 1)];
            s.vals = (const float*)d_in[4 + g];
            s.off  = dir ? offN[g] : offP[g];
            s.pairs = dir ? pairsN[g] : pairsP[g];
            s.staged = stagedBase + soff;
            soff += (size_t)nnz[g];
        }

    // ---- CSR build: count -> scan -> partition -> permute ----
    countB_kernel<<<dim3(NC, 8), 512, 0, stream>>>(G);
    scanB_kernel<<<8, 512, 0, stream>>>(G);
    partition_kernel<<<dim3(NC, 8), 512, 0, stream>>>(G);
    permute_kernel<<<pbTot, 512, 0, stream>>>(G);

    // ---- propagation ----
    size_t out_off[4]; size_t oo = 0;
    for (int g = 0; g < 4; ++g) { out_off[g] = oo; oo += (size_t)Ns[g] * D; }

    if (tierA) {
        // one cvt dispatch, then 2 fused spmm dispatches per layer
        CvtG4 C; int cb = 0;
        for (int g = 0; g < 4; ++g) {
            int n8 = Ns[g] * D / 8;
            C.c[g] = { (const float*)d_in[g], (uint4*)ebfG[g], n8, cb };
            cb += (n8 + 255) / 256;
        }
        cvt_bf16_kernel<<<cb, 256, 0, stream>>>(C);

        int pb = 0, nb = 0;
        for (int g = 0; g < 4; ++g) { pb += (Ps[g] + 3) / 4; nb += (Ns[g] + 3) / 4; }

        auto mkP = [&](const unsigned short* const xs[4]) {
            SpmmG4 T; int base = 0;
            for (int g = 0; g < 4; ++g) {
                T.g[g] = { xs[g], tG[g], nullptr, nullptr, nullptr, nullptr,
                           offP[g], pairsP[g], Ps[g], base };
                base += (Ps[g] + 3) / 4;
            }
            return T;
        };
        auto mkN0 = [&](unsigned short* const ys[4]) {
            SpmmG4 T; int base = 0;
            for (int g = 0; g < 4; ++g) {
                T.g[g] = { tG[g], ys[g], nullptr, nullptr, nullptr, nullptr,
                           offN[g], pairsN[g], Ns[g], base };
                base += (Ns[g] + 3) / 4;
            }
            return T;
        };
        SpmmG4 TP1 = mkP((const unsigned short* const*)ebfG);
        SpmmG4 TP2 = mkP((const unsigned short* const*)c1G);
        SpmmG4 TP3 = mkP((const unsigned short* const*)c2G);
        SpmmG4 TN1 = mkN0(c1G);
        SpmmG4 TN2 = mkN0(c2G);
        SpmmG4 TN3; { int base = 0;
            for (int g = 0; g < 4; ++g) {
                TN3.g[g] = { tG[g], ebfG[g], c1G[g], c2G[g],
                             (float*)d_out + out_off[g], nullptr,
                             offN[g], pairsN[g], Ns[g], base };
                base += (Ns[g] + 3) / 4;
            }
        }
        spmm_kernel<0><<<pb, 256, 0, stream>>>(TP1);
        spmm_kernel<0><<<nb, 256, 0, stream>>>(TN1);
        spmm_kernel<0><<<pb, 256, 0, stream>>>(TP2);
        spmm_kernel<0><<<nb, 256, 0, stream>>>(TN2);
        spmm_kernel<0><<<pb, 256, 0, stream>>>(TP3);
        spmm_kernel<3><<<nb, 256, 0, stream>>>(TN3);
    } else {
        // shared-buffer fallback: per-graph sequential, 1-entry tables, fp32
        const int BIG = 0x7FFFFFFF;
        for (int g = 0; g < 4; ++g) {
            const float* emb = (const float*)d_in[g];
            float* outg = (float*)d_out + out_off[g];
            const int N = Ns[g], P = Ps[g];
            int n8 = N * D / 8;
            CvtG4 C;
            C.c[0] = { emb, (uint4*)ebfG[g], n8, 0 };
            for (int i = 1; i < 4; ++i) C.c[i].blkBase = BIG;
            cvt_bf16_kernel<<<(n8 + 255) / 256, 256, 0, stream>>>(C);

            SpmmG4 TP, TN;
            TP.g[0] = { ebfG[g], tG[g], nullptr, nullptr, nullptr, nullptr,
                        offP[g], pairsP[g], P, 0 };
            TN.g[0] = { tG[g], ebfG[g], nullptr, nullptr, outg, emb,
                        offN[g], pairsN[g], N, 0 };
            for (int i = 1; i < 4; ++i) { TP.g[i].blkBase = BIG; TN.g[i].blkBase = BIG; }
            int gp = (P + 3) / 4, gn = (N + 3) / 4;
            spmm_kernel<0><<<gp, 256, 0, stream>>>(TP);
            spmm_kernel<4><<<gn, 256, 0, stream>>>(TN);
            spmm_kernel<0><<<gp, 256, 0, stream>>>(TP);
            spmm_kernel<5><<<gn, 256, 0, stream>>>(TN);
            spmm_kernel<0><<<gp, 256, 0, stream>>>(TP);
            spmm_kernel<6><<<gn, 256, 0, stream>>>(TN);
        }
    }
}

// Round 10
// 1170.026 us; speedup vs baseline: 1.1652x; 1.0035x over previous
//
#include <hip/hip_runtime.h>

// ---------------------------------------------------------------------------
// LightGCN-style propagation, 4 independent bipartite graphs.
// R13: cache-pollution hygiene + count/cvt fusion.
// R12 post-mortem: top dispatch is MODE3 (161us, FETCH 519MB, WRITE=fp32 out).
// Gather W (71.7MB) >> 4MB/XCD L2 -> capacity-miss bound; affinity/blocking
// can't help (misses ~ refs*(1-C/W) regardless of XCD split). Remaining:
// (a) zero-reuse streams churn the gather L2: nt-load MODE3's ebf/c1/c2
//     reads, nt-store ALL spmm/cvt outputs (full-line contiguous writes ->
//     write-combine to fabric, no allocate). pairs stays cached (R9 lesson:
//     shared by the block's 4 rows).
// (b) fuse cvt into the countB dispatch (countB alone = 2 blocks/CU,
//     latency-starved; cvt is independent) -> one 1-D grid, bid<512 counts,
//     rest converts. -1 launch, ~15us overlap.
// Build (R6-R12): countB -> scanB -> partition (staged int2, nt reads,
// 512thr) -> permute (LDS counting sort -> CSR off[] + u32 pairs
// src|bf15val<<17). SpMM: bf16 gather, quarter-wave, 16-edge unroll,
// per-layer N-output buffers (e_bf,c1,c2), MODE3 final fp32.
// ---------------------------------------------------------------------------

#define D 128
#define NC 64          // partition chunks per stream
#define TILE_CAP 7168  // permute LDS tile capacity (edges)
#define MAX_NB 512     // max dest-buckets per stream

// native clang vectors (accepted by __builtin_nontemporal_* / packed ops)
typedef int   vint4   __attribute__((ext_vector_type(4)));
typedef float vfloat4 __attribute__((ext_vector_type(4)));
typedef float vfloat2 __attribute__((ext_vector_type(2)));

// ---- bf16 helpers (RNE pack, bit-shift unpack) ----
__device__ __forceinline__ unsigned f2bf(float f) {
    unsigned u = __float_as_uint(f);
    u += 0x7FFFu + ((u >> 16) & 1u);
    return u >> 16;
}
__device__ __forceinline__ float bflo(unsigned u) { return __uint_as_float(u << 16); }
__device__ __forceinline__ float bfhi(unsigned u) { return __uint_as_float(u & 0xFFFF0000u); }

// ---- nontemporal helpers ----
__device__ __forceinline__ uint4 ld_nt_u4(const uint4* p) {
    vint4 w = __builtin_nontemporal_load((const vint4*)p);
    uint4 v; v.x = (unsigned)w.x; v.y = (unsigned)w.y;
    v.z = (unsigned)w.z; v.w = (unsigned)w.w; return v;
}
__device__ __forceinline__ void st_nt_u4(uint4* p, uint4 v) {
    vint4 w; w.x = (int)v.x; w.y = (int)v.y; w.z = (int)v.z; w.w = (int)v.w;
    __builtin_nontemporal_store(w, (vint4*)p);
}
__device__ __forceinline__ void st_nt_f4(float4* p, float4 v) {
    vfloat4 w; w.x = v.x; w.y = v.y; w.z = v.z; w.w = v.w;
    __builtin_nontemporal_store(w, (vfloat4*)p);
}

// ---- cvt desc ----
struct CvtG { const float* x; uint4* y; int n8, blkBase; };
struct CvtG4 { CvtG c[4]; };

// standalone cvt (fallback path, 256 thr)
__global__ __launch_bounds__(256) void cvt_bf16_kernel(CvtG4 Cd)
{
    int blk = blockIdx.x;
    int gi = (blk >= Cd.c[1].blkBase) + (blk >= Cd.c[2].blkBase)
           + (blk >= Cd.c[3].blkBase);
    const CvtG E = Cd.c[gi];
    int i = (blk - E.blkBase) * 256 + threadIdx.x;
    if (i >= E.n8) return;
    const float4* xp = (const float4*)E.x + (size_t)i * 2;
    float4 a = xp[0], b = xp[1];
    uint4 o;
    o.x = f2bf(a.x) | (f2bf(a.y) << 16);
    o.y = f2bf(a.z) | (f2bf(a.w) << 16);
    o.z = f2bf(b.x) | (f2bf(b.y) << 16);
    o.w = f2bf(b.z) | (f2bf(b.w) << 16);
    st_nt_u4(&E.y[i], o);
}

// ---- per-(graph,dir) stream descriptor ----
struct BStream {
    const int* dst; const int* src; const float* vals;
    int2* staged;        // K3 output (src|dl<<17, val f32), bucket-major
    unsigned* pairs;     // final CSR pairs, packed src|bf15val<<17
    int* off;            // final CSR offsets [n+1]
    int nnz, n, wshift, nb, cbase;
};
struct B8 {
    BStream s[8];
    int* cnt;            // [sum(nb+1)][NC]: counts -> cursor starts (K2 rewrite)
    int* gBB;            // [sum(nb+1)]: bucket bases + per-stream sentinel
    int pb[8];           // permute-block base per stream
};

// ---- K1: fused coarse-bucket histogram + fp32->bf16 cvt ----
// bid < countBlks (=NC*8): count chunk (bid>>3) of stream (bid&7).
// bid >= countBlks: cvt block (512 thr, 1 uint4/thread).
struct CntCvt { B8 G; CvtG4 C; int countBlks; };

__global__ __launch_bounds__(512) void count_cvt_kernel(CntCvt A)
{
    int bid = blockIdx.x;
    if (bid < A.countBlks) {
        const BStream S = A.G.s[bid & 7];
        int c = bid >> 3;
        __shared__ int h[MAX_NB];
        for (int i = threadIdx.x; i < S.nb; i += 512) h[i] = 0;
        __syncthreads();
        int len = (((S.nnz + NC - 1) / NC) + 3) & ~3;
        int e0 = c * len, e1 = min(S.nnz, e0 + len);
        if (e0 < e1) {
            int nq = (e1 - e0) >> 2;
            const vint4* dq = (const vint4*)(S.dst + e0);
            for (int i = threadIdx.x; i < nq; i += 512) {
                vint4 v = __builtin_nontemporal_load(&dq[i]);
                atomicAdd(&h[v.x >> S.wshift], 1);
                atomicAdd(&h[v.y >> S.wshift], 1);
                atomicAdd(&h[v.z >> S.wshift], 1);
                atomicAdd(&h[v.w >> S.wshift], 1);
            }
            for (int e = e0 + (nq << 2) + (int)threadIdx.x; e < e1; e += 512)
                atomicAdd(&h[S.dst[e] >> S.wshift], 1);
        }
        __syncthreads();
        int* out = A.G.cnt + (size_t)S.cbase * NC;
        for (int i = threadIdx.x; i < S.nb; i += 512)
            out[(size_t)i * NC + c] = h[i];
    } else {
        int cb = bid - A.countBlks;
        int gi = (cb >= A.C.c[1].blkBase) + (cb >= A.C.c[2].blkBase)
               + (cb >= A.C.c[3].blkBase);
        const CvtG E = A.C.c[gi];
        int i = (cb - E.blkBase) * 512 + threadIdx.x;
        if (i >= E.n8) return;
        const float4* xp = (const float4*)E.x + (size_t)i * 2;
        float4 a = xp[0], b = xp[1];
        uint4 o;
        o.x = f2bf(a.x) | (f2bf(a.y) << 16);
        o.y = f2bf(a.z) | (f2bf(a.w) << 16);
        o.z = f2bf(b.x) | (f2bf(b.y) << 16);
        o.w = f2bf(b.z) | (f2bf(b.w) << 16);
        st_nt_u4(&E.y[i], o);
    }
}

// ---- K2: bucket totals + exscan -> bases and per-chunk cursor starts ----
__global__ __launch_bounds__(512) void scanB_kernel(B8 G)
{
    const BStream S = G.s[blockIdx.x];
    int* cnt = G.cnt + (size_t)S.cbase * NC;
    int* bb  = G.gBB + S.cbase;
    __shared__ int wsum[8];
    int b = threadIdx.x;
    int t = 0;
    if (b < S.nb) {
        int* row = cnt + (size_t)b * NC;
        int run = 0;
        #pragma unroll
        for (int c = 0; c < NC; ++c) { int v = row[c]; row[c] = run; run += v; }
        t = run;
    }
    int lane = b & 63, w = b >> 6;
    int x = t;
    #pragma unroll
    for (int s = 1; s < 64; s <<= 1) {
        int y = __shfl_up(x, s, 64);
        if (lane >= s) x += y;
    }
    if (lane == 63) wsum[w] = x;
    __syncthreads();
    if (b == 0) {
        int run = 0;
        #pragma unroll
        for (int i = 0; i < 8; ++i) { int v = wsum[i]; wsum[i] = run; run += v; }
    }
    __syncthreads();
    int excl = wsum[w] + x - t;
    if (b < S.nb) {
        bb[b] = excl;
        int* row = cnt + (size_t)b * NC;
        #pragma unroll
        for (int c = 0; c < NC; ++c) row[c] += excl;
    }
    if (b == 0) { bb[S.nb] = S.nnz; S.off[S.n] = S.nnz; }
}

// ---- K3: partition edges bucket-major, staged (src|dl<<17, val f32) ----
__global__ __launch_bounds__(512) void partition_kernel(B8 G)
{
    const BStream S = G.s[blockIdx.y];
    int c = blockIdx.x;
    __shared__ int cur[MAX_NB];
    const int* cs = G.cnt + (size_t)S.cbase * NC;
    for (int i = threadIdx.x; i < S.nb; i += 512) cur[i] = cs[(size_t)i * NC + c];
    __syncthreads();
    int len = (((S.nnz + NC - 1) / NC) + 3) & ~3;
    int e0 = c * len, e1 = min(S.nnz, e0 + len);
    if (e0 >= e1) return;
    int smask = (1 << S.wshift) - 1;
    int nq = (e1 - e0) >> 2;
    const vint4*   dq = (const vint4*)(S.dst + e0);
    const vint4*   sq = (const vint4*)(S.src + e0);
    const vfloat4* vq = (const vfloat4*)(S.vals + e0);
    for (int i = threadIdx.x; i < nq; i += 512) {
        vint4 dv = __builtin_nontemporal_load(&dq[i]);
        vint4 sv = __builtin_nontemporal_load(&sq[i]);
        vfloat4 vv = __builtin_nontemporal_load(&vq[i]);
        int p;
        p = atomicAdd(&cur[dv.x >> S.wshift], 1);
        S.staged[p] = make_int2(sv.x | ((dv.x & smask) << 17), __float_as_int(vv.x));
        p = atomicAdd(&cur[dv.y >> S.wshift], 1);
        S.staged[p] = make_int2(sv.y | ((dv.y & smask) << 17), __float_as_int(vv.y));
        p = atomicAdd(&cur[dv.z >> S.wshift], 1);
        S.staged[p] = make_int2(sv.z | ((dv.z & smask) << 17), __float_as_int(vv.z));
        p = atomicAdd(&cur[dv.w >> S.wshift], 1);
        S.staged[p] = make_int2(sv.w | ((dv.w & smask) << 17), __float_as_int(vv.w));
    }
    for (int e = e0 + (nq << 2) + (int)threadIdx.x; e < e1; e += 512) {
        int d = S.dst[e];
        int p = atomicAdd(&cur[d >> S.wshift], 1);
        S.staged[p] = make_int2(S.src[e] | ((d & smask) << 17), __float_as_int(S.vals[e]));
    }
}

// ---- K4: per-bucket dest-sort through LDS; writes CSR off[] + u32 pairs ----
__global__ __launch_bounds__(512) void permute_kernel(B8 G)
{
    int gb = blockIdx.x;
    int s = 0;
    #pragma unroll
    for (int i = 1; i < 8; ++i) s += (gb >= G.pb[i]);
    const BStream S = G.s[s];
    int b = gb - G.pb[s];
    const int* bb = G.gBB + S.cbase;
    int B0 = bb[b], B1 = bb[b + 1];
    int cnt = B1 - B0;
    int span = 1 << S.wshift;
    int dbase = b << S.wshift;

    __shared__ unsigned tile[TILE_CAP];
    __shared__ int cursor[MAX_NB];
    __shared__ int wsum[8];
    int tid = threadIdx.x;

    for (int i = tid; i < span; i += 512) cursor[i] = 0;
    __syncthreads();
    for (int i = B0 + tid; i < B1; i += 512)
        atomicAdd(&cursor[((unsigned)S.staged[i].x) >> 17], 1);
    __syncthreads();

    // exclusive scan over span (<=512) counts
    int v = (tid < span) ? cursor[tid] : 0;
    int lane = tid & 63, w = tid >> 6;
    int x = v;
    #pragma unroll
    for (int st = 1; st < 64; st <<= 1) {
        int y = __shfl_up(x, st, 64);
        if (lane >= st) x += y;
    }
    if (lane == 63) wsum[w] = x;
    __syncthreads();
    if (tid == 0) {
        int run = 0;
        #pragma unroll
        for (int i = 0; i < 8; ++i) { int t = wsum[i]; wsum[i] = run; run += t; }
    }
    __syncthreads();
    int excl = wsum[w] + x - v;
    __syncthreads();
    if (tid < span) {
        int d = dbase + tid;
        if (d < S.n) S.off[d] = B0 + excl;
        cursor[tid] = excl;
    }
    __syncthreads();

    if (cnt <= TILE_CAP) {
        for (int i = B0 + tid; i < B1; i += 512) {
            int2 pe = S.staged[i];
            int dl = ((unsigned)pe.x) >> 17;
            int p = atomicAdd(&cursor[dl], 1);
            unsigned bf15 = f2bf(__int_as_float(pe.y)) & 0x7FFFu;
            tile[p] = ((unsigned)pe.x & 0x1FFFFu) | (bf15 << 17);
        }
        __syncthreads();
        for (int i = tid; i < cnt; i += 512) S.pairs[B0 + i] = tile[i];
    } else {
        // statistically-never fallback; staged != pairs so no in-place hazard
        for (int i = B0 + tid; i < B1; i += 512) {
            int2 pe = S.staged[i];
            int dl = ((unsigned)pe.x) >> 17;
            int p = atomicAdd(&cursor[dl], 1);
            unsigned bf15 = f2bf(__int_as_float(pe.y)) & 0x7FFFu;
            S.pairs[B0 + p] = ((unsigned)pe.x & 0x1FFFFu) | (bf15 << 17);
        }
    }
}

// ---- gather SpMM, fused over graphs via desc table ----
//   MODE 0: y = acc                               (all P-sides, N L1/L2)
//   MODE 3: out = (ebf + c1 + c2 + acc) * 0.25    (N L3, fp32 final)
// fp32 fallback modes (shared-buffer path):
//   MODE 4: y = acc; out = aux + acc
//   MODE 5: y = acc; out += acc
//   MODE 6: out = (out + acc) * 0.25
struct SpmmG {
    const unsigned short* x;   // bf16 gather source [n_src][128]
    unsigned short* y;         // MODE0/4/5 write target; MODE3: e_bf (read)
    const unsigned short* r1;  // MODE3: c1
    const unsigned short* r2;  // MODE3: c2
    float* out;                // fp32 [n_dst][128]
    const float* aux;          // fp32 emb (MODE 4)
    const int* off; const unsigned* pairs;
    int n_dst, blkBase;
};
struct SpmmG4 { SpmmG g[4]; };

__device__ __forceinline__ float pval(unsigned p) {
    return __uint_as_float((p >> 1) & 0xFFFF0000u);
}
__device__ __forceinline__ void fma8(vfloat2 a[4], uint4 g, float v) {
    vfloat2 vv; vv.x = v; vv.y = v;
    vfloat2 u;
    u.x = bflo(g.x); u.y = bfhi(g.x); a[0] = u * vv + a[0];
    u.x = bflo(g.y); u.y = bfhi(g.y); a[1] = u * vv + a[1];
    u.x = bflo(g.z); u.y = bfhi(g.z); a[2] = u * vv + a[2];
    u.x = bflo(g.w); u.y = bfhi(g.w); a[3] = u * vv + a[3];
}

template<int MODE>
__global__ __launch_bounds__(256) void spmm_kernel(SpmmG4 Gd)
{
    int blk = blockIdx.x;
    int gi = (blk >= Gd.g[1].blkBase) + (blk >= Gd.g[2].blkBase)
           + (blk >= Gd.g[3].blkBase);
    const SpmmG E = Gd.g[gi];
    int row = (blk - E.blkBase) * 4 + (threadIdx.x >> 6);
    if (row >= E.n_dst) return;
    int lane = threadIdx.x & 63;
    int q   = lane >> 4;     // quarter 0..3 -> edge j+q
    int l16 = lane & 15;     // elems l16*8 .. l16*8+7

    int s = E.off[row], e = E.off[row + 1];
    vfloat2 acc2[4];
    #pragma unroll
    for (int k = 0; k < 4; ++k) { acc2[k].x = 0.f; acc2[k].y = 0.f; }

    int j = s;
    for (; j + 15 < e; j += 16) {          // 16 edges/iter, 4 gathers in flight
        unsigned p0 = E.pairs[j + q];
        unsigned p1 = E.pairs[j + 4 + q];
        unsigned p2 = E.pairs[j + 8 + q];
        unsigned p3 = E.pairs[j + 12 + q];
        uint4 g0 = ((const uint4*)(E.x + ((long)(p0 & 0x1FFFFu) << 7)))[l16];
        uint4 g1 = ((const uint4*)(E.x + ((long)(p1 & 0x1FFFFu) << 7)))[l16];
        uint4 g2 = ((const uint4*)(E.x + ((long)(p2 & 0x1FFFFu) << 7)))[l16];
        uint4 g3 = ((const uint4*)(E.x + ((long)(p3 & 0x1FFFFu) << 7)))[l16];
        fma8(acc2, g0, pval(p0));
        fma8(acc2, g1, pval(p1));
        fma8(acc2, g2, pval(p2));
        fma8(acc2, g3, pval(p3));
    }
    for (; j + 7 < e; j += 8) {            // 8 edges/iter
        unsigned p0 = E.pairs[j + q];
        unsigned p1 = E.pairs[j + 4 + q];
        uint4 g0 = ((const uint4*)(E.x + ((long)(p0 & 0x1FFFFu) << 7)))[l16];
        uint4 g1 = ((const uint4*)(E.x + ((long)(p1 & 0x1FFFFu) << 7)))[l16];
        fma8(acc2, g0, pval(p0));
        fma8(acc2, g1, pval(p1));
    }
    for (; j < e; j += 4) {                // predicated tail quad
        if (j + q < e) {
            unsigned p = E.pairs[j + q];
            uint4 g = ((const uint4*)(E.x + ((long)(p & 0x1FFFFu) << 7)))[l16];
            fma8(acc2, g, pval(p));
        }
    }

    float acc[8] = { acc2[0].x, acc2[0].y, acc2[1].x, acc2[1].y,
                     acc2[2].x, acc2[2].y, acc2[3].x, acc2[3].y };
    #pragma unroll
    for (int k = 0; k < 8; ++k) {          // combine 4 quarter partials
        acc[k] += __shfl_xor(acc[k], 16);
        acc[k] += __shfl_xor(acc[k], 32);
    }
    if (q != 0) return;
    long rb = (long)row << 7;

    if (MODE == 0 || MODE == 4 || MODE == 5) {
        uint4 o;
        o.x = f2bf(acc[0]) | (f2bf(acc[1]) << 16);
        o.y = f2bf(acc[2]) | (f2bf(acc[3]) << 16);
        o.z = f2bf(acc[4]) | (f2bf(acc[5]) << 16);
        o.w = f2bf(acc[6]) | (f2bf(acc[7]) << 16);
        st_nt_u4((uint4*)(E.y + rb) + l16, o);
    }
    if (MODE == 3) {
        uint4 pe = ld_nt_u4((const uint4*)(E.y  + rb) + l16);   // e_bf
        uint4 pc = ld_nt_u4((const uint4*)(E.r1 + rb) + l16);   // c1
        uint4 pd = ld_nt_u4((const uint4*)(E.r2 + rb) + l16);   // c2
        float4* op = (float4*)(E.out + rb) + l16 * 2;
        float4 a0, a1;
        a0.x = (acc[0] + bflo(pe.x) + bflo(pc.x) + bflo(pd.x)) * 0.25f;
        a0.y = (acc[1] + bfhi(pe.x) + bfhi(pc.x) + bfhi(pd.x)) * 0.25f;
        a0.z = (acc[2] + bflo(pe.y) + bflo(pc.y) + bflo(pd.y)) * 0.25f;
        a0.w = (acc[3] + bfhi(pe.y) + bfhi(pc.y) + bfhi(pd.y)) * 0.25f;
        a1.x = (acc[4] + bflo(pe.z) + bflo(pc.z) + bflo(pd.z)) * 0.25f;
        a1.y = (acc[5] + bfhi(pe.z) + bfhi(pc.z) + bfhi(pd.z)) * 0.25f;
        a1.z = (acc[6] + bflo(pe.w) + bflo(pc.w) + bflo(pd.w)) * 0.25f;
        a1.w = (acc[7] + bfhi(pe.w) + bfhi(pc.w) + bfhi(pd.w)) * 0.25f;
        st_nt_f4(op, a0); st_nt_f4(op + 1, a1);
    } else if (MODE == 4) {
        const float4* ap = (const float4*)(E.aux + rb) + l16 * 2;
        float4* op = (float4*)(E.out + rb) + l16 * 2;
        float4 a0 = ap[0], a1 = ap[1];
        a0.x += acc[0]; a0.y += acc[1]; a0.z += acc[2]; a0.w += acc[3];
        a1.x += acc[4]; a1.y += acc[5]; a1.z += acc[6]; a1.w += acc[7];
        st_nt_f4(op, a0); st_nt_f4(op + 1, a1);
    } else if (MODE == 5) {
        float4* op = (float4*)(E.out + rb) + l16 * 2;
        float4 a0 = op[0], a1 = op[1];
        a0.x += acc[0]; a0.y += acc[1]; a0.z += acc[2]; a0.w += acc[3];
        a1.x += acc[4]; a1.y += acc[5]; a1.z += acc[6]; a1.w += acc[7];
        op[0] = a0; op[1] = a1;
    } else if (MODE == 6) {
        float4* op = (float4*)(E.out + rb) + l16 * 2;
        float4 a0 = op[0], a1 = op[1];
        a0.x = (a0.x + acc[0]) * 0.25f; a0.y = (a0.y + acc[1]) * 0.25f;
        a0.z = (a0.z + acc[2]) * 0.25f; a0.w = (a0.w + acc[3]) * 0.25f;
        a1.x = (a1.x + acc[4]) * 0.25f; a1.y = (a1.y + acc[5]) * 0.25f;
        a1.z = (a1.z + acc[6]) * 0.25f; a1.w = (a1.w + acc[7]) * 0.25f;
        op[0] = a0; op[1] = a1;
    }
}

extern "C" void kernel_launch(void* const* d_in, const int* in_sizes, int n_in,
                              void* d_out, int out_size, void* d_ws, size_t ws_size,
                              hipStream_t stream)
{
    static const int Ns[4] = {100000, 40000, 20000, 10000};
    static const int Ps[4] = { 40000, 100000, 100000, 40000};
    const int maxN = 100000, maxP = 100000;

    int nnz[4];
    for (int g = 0; g < 4; ++g) nnz[g] = in_sizes[4 + g];

    // wshift: largest span (pow2, <=512) with expected edges <= 5120/bucket
    auto calc_ws = [](int n, int m) {
        int ws = 0;
        while (ws < 9 && (double)m * (double)(1 << (ws + 1)) <= 5120.0 * n) ++ws;
        while (((n + (1 << ws) - 1) >> ws) > MAX_NB) ++ws;
        return ws;
    };

    // ---- stream geometry (pointer-free) ----
    B8 G;
    int cbase = 0, pbTot = 0;
    for (int g = 0; g < 4; ++g)
        for (int dir = 0; dir < 2; ++dir) {
            BStream& s = G.s[2 * g + dir];
            s.nnz = nnz[g];
            s.n   = dir ? Ns[g] : Ps[g];
            s.wshift = calc_ws(s.n, s.nnz);
            s.nb = (s.n + (1 << s.wshift) - 1) >> s.wshift;
            s.cbase = cbase;
            G.pb[2 * g + dir] = pbTot;
            cbase += s.nb + 1;
            pbTot += s.nb;
        }

    // ---- ws budget: tier A = per-graph {e_bf,c1,c2,t} ----
    auto padded = [](size_t b) { return (b + 255) & ~(size_t)255; };
    size_t common = 0;
    for (int g = 0; g < 4; ++g) common += padded((size_t)(Ps[g] + 1) * 4)
                                        + padded((size_t)(Ns[g] + 1) * 4);
    for (int g = 0; g < 4; ++g) common += 2 * padded((size_t)nnz[g] * 4);
    common += padded((size_t)cbase * NC * 4) + padded((size_t)cbase * 4);
    size_t needA = common;
    for (int g = 0; g < 4; ++g) needA += 3 * padded((size_t)Ns[g] * D * 2)
                                       + padded((size_t)Ps[g] * D * 2);
    bool tierA = needA <= ws_size;

    // ---- workspace carve ----
    char* wp = (char*)d_ws;
    auto alloc = [&](size_t bytes) -> void* {
        void* p = (void*)wp; wp += (bytes + 255) & ~(size_t)255; return p;
    };
    unsigned short *ebfG[4], *c1G[4], *c2G[4], *tG[4];
    if (tierA) {
        for (int g = 0; g < 4; ++g) {
            ebfG[g] = (unsigned short*)alloc((size_t)Ns[g] * D * 2);
            c1G[g]  = (unsigned short*)alloc((size_t)Ns[g] * D * 2);
            c2G[g]  = (unsigned short*)alloc((size_t)Ns[g] * D * 2);
            tG[g]   = (unsigned short*)alloc((size_t)Ps[g] * D * 2);
        }
    } else {
        unsigned short* cur = (unsigned short*)alloc((size_t)maxN * D * 2);
        unsigned short* t   = (unsigned short*)alloc((size_t)maxP * D * 2);
        for (int g = 0; g < 4; ++g) {
            ebfG[g] = c1G[g] = c2G[g] = cur; tG[g] = t;
        }
    }
    int* offP[4]; int* offN[4]; unsigned* pairsP[4]; unsigned* pairsN[4];
    for (int g = 0; g < 4; ++g) {
        offP[g] = (int*)alloc((size_t)(Ps[g] + 1) * sizeof(int));
        offN[g] = (int*)alloc((size_t)(Ns[g] + 1) * sizeof(int));
    }
    for (int g = 0; g < 4; ++g) {
        pairsP[g] = (unsigned*)alloc((size_t)nnz[g] * sizeof(unsigned));
        pairsN[g] = (unsigned*)alloc((size_t)nnz[g] * sizeof(unsigned));
    }
    G.cnt = (int*)alloc((size_t)cbase * NC * sizeof(int));
    G.gBB = (int*)alloc((size_t)cbase * sizeof(int));

    // staged packed int2 -> d_out (fully consumed by permute before spmm)
    int2* stagedBase = (int2*)d_out;
    size_t soff = 0;
    for (int g = 0; g < 4; ++g)
        for (int dir = 0; dir < 2; ++dir) {
            BStream& s = G.s[2 * g + dir];
            s.dst  = (const int*)d_in[8 + 2 * g + (dir ? 1 : 0)];
            s.src  = (const int*)d_in[8 + 2 * g + (dir ? 0 : 1)];
            s.vals = (const float*)d_in[4 + g];
            s.off  = dir ? offN[g] : offP[g];
            s.pairs = dir ? pairsN[g] : pairsP[g];
            s.staged = stagedBase + soff;
            soff += (size_t)nnz[g];
        }

    // ---- CSR build: (count+cvt fused) -> scan -> partition -> permute ----
    CntCvt CC; CC.G = G; CC.countBlks = NC * 8;
    int cvtBlks = 0;
    if (tierA) {
        for (int g = 0; g < 4; ++g) {
            int n8 = Ns[g] * D / 8;
            CC.C.c[g] = { (const float*)d_in[g], (uint4*)ebfG[g], n8, cvtBlks };
            cvtBlks += (n8 + 511) / 512;
        }
    } else {
        for (int g = 0; g < 4; ++g) CC.C.c[g] = { nullptr, nullptr, 0, 0x7FFFFFFF };
    }
    count_cvt_kernel<<<CC.countBlks + cvtBlks, 512, 0, stream>>>(CC);
    scanB_kernel<<<8, 512, 0, stream>>>(G);
    partition_kernel<<<dim3(NC, 8), 512, 0, stream>>>(G);
    permute_kernel<<<pbTot, 512, 0, stream>>>(G);

    // ---- propagation ----
    size_t out_off[4]; size_t oo = 0;
    for (int g = 0; g < 4; ++g) { out_off[g] = oo; oo += (size_t)Ns[g] * D; }

    if (tierA) {
        int pb = 0, nb = 0;
        for (int g = 0; g < 4; ++g) { pb += (Ps[g] + 3) / 4; nb += (Ns[g] + 3) / 4; }

        auto mkP = [&](const unsigned short* const xs[4]) {
            SpmmG4 T; int base = 0;
            for (int g = 0; g < 4; ++g) {
                T.g[g] = { xs[g], tG[g], nullptr, nullptr, nullptr, nullptr,
                           offP[g], pairsP[g], Ps[g], base };
                base += (Ps[g] + 3) / 4;
            }
            return T;
        };
        auto mkN0 = [&](unsigned short* const ys[4]) {
            SpmmG4 T; int base = 0;
            for (int g = 0; g < 4; ++g) {
                T.g[g] = { tG[g], ys[g], nullptr, nullptr, nullptr, nullptr,
                           offN[g], pairsN[g], Ns[g], base };
                base += (Ns[g] + 3) / 4;
            }
            return T;
        };
        SpmmG4 TP1 = mkP((const unsigned short* const*)ebfG);
        SpmmG4 TP2 = mkP((const unsigned short* const*)c1G);
        SpmmG4 TP3 = mkP((const unsigned short* const*)c2G);
        SpmmG4 TN1 = mkN0(c1G);
        SpmmG4 TN2 = mkN0(c2G);
        SpmmG4 TN3; { int base = 0;
            for (int g = 0; g < 4; ++g) {
                TN3.g[g] = { tG[g], ebfG[g], c1G[g], c2G[g],
                             (float*)d_out + out_off[g], nullptr,
                             offN[g], pairsN[g], Ns[g], base };
                base += (Ns[g] + 3) / 4;
            }
        }
        spmm_kernel<0><<<pb, 256, 0, stream>>>(TP1);
        spmm_kernel<0><<<nb, 256, 0, stream>>>(TN1);
        spmm_kernel<0><<<pb, 256, 0, stream>>>(TP2);
        spmm_kernel<0><<<nb, 256, 0, stream>>>(TN2);
        spmm_kernel<0><<<pb, 256, 0, stream>>>(TP3);
        spmm_kernel<3><<<nb, 256, 0, stream>>>(TN3);
    } else {
        // shared-buffer fallback: per-graph sequential, 1-entry tables, fp32
        const int BIG = 0x7FFFFFFF;
        for (int g = 0; g < 4; ++g) {
            const float* emb = (const float*)d_in[g];
            float* outg = (float*)d_out + out_off[g];
            const int N = Ns[g], P = Ps[g];
            int n8 = N * D / 8;
            CvtG4 C;
            C.c[0] = { emb, (uint4*)ebfG[g], n8, 0 };
            for (int i = 1; i < 4; ++i) C.c[i].blkBase = BIG;
            cvt_bf16_kernel<<<(n8 + 255) / 256, 256, 0, stream>>>(C);

            SpmmG4 TP, TN;
            TP.g[0] = { ebfG[g], tG[g], nullptr, nullptr, nullptr, nullptr,
                        offP[g], pairsP[g], P, 0 };
            TN.g[0] = { tG[g], ebfG[g], nullptr, nullptr, outg, emb,
                        offN[g], pairsN[g], N, 0 };
            for (int i = 1; i < 4; ++i) { TP.g[i].blkBase = BIG; TN.g[i].blkBase = BIG; }
            int gp = (P + 3) / 4, gn = (N + 3) / 4;
            spmm_kernel<0><<<gp, 256, 0, stream>>>(TP);
            spmm_kernel<4><<<gn, 256, 0, stream>>>(TN);
            spmm_kernel<0><<<gp, 256, 0, stream>>>(TP);
            spmm_kernel<5><<<gn, 256, 0, stream>>>(TN);
            spmm_kernel<0><<<gp, 256, 0, stream>>>(TP);
            spmm_kernel<6><<<gn, 256, 0, stream>>>(TN);
        }
    }
}